// Round 1
// baseline (515.822 us; speedup 1.0000x reference)
//
#include <hip/hip_runtime.h>

typedef unsigned short u16;
typedef __attribute__((ext_vector_type(8))) short bf16x8;
typedef __attribute__((ext_vector_type(4))) float f32x4;

constexpr int B_ = 2, C_ = 128, H_ = 256, W_ = 256, P_ = H_ * W_;
constexpr int HP_ = 258, WP_ = 258;

__device__ __forceinline__ float bf2f(u16 u) {
  union { unsigned int i; float f; } v; v.i = ((unsigned int)u) << 16; return v.f;
}
__device__ __forceinline__ u16 f2bf(float f) {
  union { float f; unsigned int i; } v; v.f = f;
  return (u16)((v.i + 0x7fffu + ((v.i >> 16) & 1u)) >> 16);  // RNE
}
__device__ __forceinline__ float gelu_f(float x) {
  return 0.5f * x * (1.0f + erff(x * 0.70710678118654752f));
}

// Zero the 1-px border of a [B][258][258][128] bf16 buffer. idx < 2*4*258*128.
__global__ __launch_bounds__(256) void border_zero(u16* __restrict__ buf) {
  int idx = blockIdx.x * 256 + threadIdx.x;
  int c = idx & 127;
  int t = idx >> 7;
  int pos = t % 258;
  int side = (t / 258) & 3;
  int b = t / (258 * 4);
  int h, w;
  if (side == 0) { h = 0;   w = pos; }
  else if (side == 1) { h = 257; w = pos; }
  else if (side == 2) { h = pos; w = 0; }
  else { h = pos; w = 257; }
  buf[(((size_t)b * HP_ + h) * WP_ + w) * C_ + c] = 0;
}

// NCHW fp32 -> NHWC bf16 (optionally into padded interior). 64ch x 64px tiles via LDS.
__global__ __launch_bounds__(256) void to_nhwc(const float* __restrict__ in, u16* __restrict__ out,
                                               int OHp, int OWp, int opad) {
  __shared__ u16 l[64 * 66];
  int tid = threadIdx.x;
  int b = blockIdx.z >> 1, c0 = (blockIdx.z & 1) * 64;
  int h = blockIdx.y, w0 = blockIdx.x * 64;
  for (int it = 0; it < 16; ++it) {
    int lin = it * 256 + tid;
    int c = lin >> 6, w = lin & 63;
    l[c * 66 + w] = f2bf(in[(((size_t)b * C_ + c0 + c) * H_ + h) * W_ + w0 + w]);
  }
  __syncthreads();
  for (int it = 0; it < 16; ++it) {
    int lin = it * 256 + tid;
    int w = lin >> 6, c = lin & 63;
    out[(((size_t)b * OHp + h + opad) * OWp + (w0 + w + opad)) * C_ + c0 + c] = l[c * 66 + w];
  }
}

// Repack all conv weights into bf16 [tap][co][ci] layouts, concatenated:
// W1 @0      : 9*128*128 = 147456   (ow1)
// W2 @147456 : 9*16*128  = 18432    (ow2, co padded 8->16 with zeros)
// W3 @165888 : 9*32*128  = 36864    (ww1)
// W4 @202752 : 128*128   = 16384    (fw1)
// W5 @219136 : 128*128   = 16384    (fw2)   total 235520
__global__ __launch_bounds__(256) void repack_weights(
    const float* __restrict__ ow1, const float* __restrict__ ow2,
    const float* __restrict__ ww1, const float* __restrict__ fw1,
    const float* __restrict__ fw2, u16* __restrict__ wb) {
  int idx = blockIdx.x * 256 + threadIdx.x;
  float v;
  if (idx < 147456) {
    int tap = idx / 16384, r = idx % 16384, co = r >> 7, ci = r & 127;
    v = ow1[((co * 128 + ci) * 3 + tap / 3) * 3 + tap % 3];
  } else if (idx < 165888) {
    int j = idx - 147456;
    int tap = j / 2048, r = j % 2048, co = r >> 7, ci = r & 127;
    v = (co < 8) ? ow2[((co * 128 + ci) * 3 + tap / 3) * 3 + tap % 3] : 0.0f;
  } else if (idx < 202752) {
    int j = idx - 165888;
    int tap = j / 4096, r = j % 4096, co = r >> 7, ci = r & 127;
    v = ww1[((co * 128 + ci) * 3 + tap / 3) * 3 + tap % 3];
  } else if (idx < 219136) {
    v = fw1[idx - 202752];
  } else {
    v = fw2[idx - 219136];
  }
  wb[idx] = f2bf(v);
}

// Implicit-GEMM conv. A: NHWC bf16 (padded if NTAPS==9). Wt: [tap][co][ci] bf16.
// M = BM pixels along w (fixed h), N = BN output channels, K = NTAPS*128.
// EPI 0: GELU -> bf16 NHWC (opad, stride OC into [OHp][OWp])
// EPI 1: fp32 -> [b][p][CoutStore], only co < CoutStore
// EPI 2: fp32 NCHW residual: out = resid + 0.3*(acc+bias)
template <int BM, int BN, int WR, int WC, int NTAPS, int EPI>
__global__ __launch_bounds__(256) void gemm_conv(
    const u16* __restrict__ A, const u16* __restrict__ Wt,
    const float* __restrict__ bias,
    u16* __restrict__ outb, float* __restrict__ outf,
    const float* __restrict__ resid,
    int Hp, int Wp, int CoutPad, int CoutStore,
    int OHp, int OWp, int opad, int OC, int NTILES) {
  constexpr int Cin = 128;
  constexpr int TM = BM / WR / 16, TN = BN / WC / 16;
  __shared__ __align__(16) u16 As[BM * 32];
  __shared__ __align__(16) u16 Bs[BN * 32];
  const int tid = threadIdx.x, lane = tid & 63, wave = tid >> 6;
  const int h = blockIdx.y, w0 = blockIdx.x * BM;
  const int b = blockIdx.z / NTILES, nt = blockIdx.z % NTILES;
  const int n0 = nt * BN;
  const int wr = wave / WC, wc = wave % WC;
  const int wm = wr * (BM / WR), wn = wc * (BN / WC);
  const int lr = lane & 15, k8 = (lane >> 4) * 8;

  f32x4 acc[TM][TN];
  for (int i = 0; i < TM; i++)
    for (int j = 0; j < TN; j++) { f32x4 z = {0.f, 0.f, 0.f, 0.f}; acc[i][j] = z; }

  for (int tap = 0; tap < NTAPS; ++tap) {
    const int ky = (NTAPS == 9) ? tap / 3 : 0;
    const int kx = (NTAPS == 9) ? tap % 3 : 0;
    const u16* Ab = A + (((size_t)b * Hp + h + ky) * Wp + (w0 + kx)) * Cin;
    const u16* Wb = Wt + ((size_t)tap * CoutPad + n0) * Cin;
    for (int c0 = 0; c0 < Cin; c0 += 32) {
      __syncthreads();
      for (int i = tid; i < BM * 4; i += 256) {
        int r = i >> 2, c8 = (i & 3) * 8;
        *(uint4*)&As[r * 32 + c8] = *(const uint4*)&Ab[r * Cin + c0 + c8];
      }
      for (int i = tid; i < BN * 4; i += 256) {
        int r = i >> 2, c8 = (i & 3) * 8;
        *(uint4*)&Bs[r * 32 + c8] = *(const uint4*)&Wb[r * Cin + c0 + c8];
      }
      __syncthreads();
      bf16x8 af[TM], bfr[TN];
#pragma unroll
      for (int i = 0; i < TM; i++) af[i] = *(const bf16x8*)&As[(wm + i * 16 + lr) * 32 + k8];
#pragma unroll
      for (int j = 0; j < TN; j++) bfr[j] = *(const bf16x8*)&Bs[(wn + j * 16 + lr) * 32 + k8];
#pragma unroll
      for (int i = 0; i < TM; i++)
#pragma unroll
        for (int j = 0; j < TN; j++)
          acc[i][j] = __builtin_amdgcn_mfma_f32_16x16x32_bf16(af[i], bfr[j], acc[i][j], 0, 0, 0);
    }
  }

#pragma unroll
  for (int i = 0; i < TM; i++) {
#pragma unroll
    for (int j = 0; j < TN; j++) {
      const int nl = wn + j * 16 + lr;
      const int co = n0 + nl;
#pragma unroll
      for (int r = 0; r < 4; r++) {
        const int ml = wm + i * 16 + (lane >> 4) * 4 + r;
        const int w = w0 + ml;
        float v = acc[i][j][r];
        if (EPI == 0) {
          v = gelu_f(v + bias[co]);
          outb[(((size_t)b * OHp + h + opad) * OWp + (w + opad)) * OC + co] = f2bf(v);
        } else if (EPI == 1) {
          if (co < CoutStore)
            outf[((size_t)b * P_ + h * W_ + w) * CoutStore + co] = v + bias[co];
        } else {
          size_t idx = ((size_t)b * OC + co) * P_ + (size_t)h * W_ + w;
          outf[idx] = resid[idx] + 0.3f * (v + bias[co]);
        }
      }
    }
  }
}

// Per-pixel: 1x1 conv 32->4 logits, softmax, 4x bilinear grid_sample over 128ch, weighted sum.
// One wave per pixel; lane handles channel pair (2*lane, 2*lane+1).
__global__ __launch_bounds__(256) void sampler(
    const float* __restrict__ offs, const u16* __restrict__ w1,
    const float* __restrict__ ww2, const float* __restrict__ wb2,
    const u16* __restrict__ keyn, u16* __restrict__ agg) {
  const int tid = threadIdx.x, lane = tid & 63, wv = tid >> 6;
  const int pix = blockIdx.x * 4 + wv;
  const int b = pix >> 16, p = pix & 65535;
  const int h = p >> 8, w = p & 255;

  const u16* w1p = w1 + (size_t)pix * 32;
  float lg[4];
#pragma unroll
  for (int k = 0; k < 4; k++) {
    float s = wb2[k];
#pragma unroll
    for (int i = 0; i < 32; i++) s += ww2[k * 32 + i] * bf2f(w1p[i]);
    lg[k] = s;
  }
  float mx = fmaxf(fmaxf(lg[0], lg[1]), fmaxf(lg[2], lg[3]));
  float e[4]; float sum = 0.f;
#pragma unroll
  for (int k = 0; k < 4; k++) { e[k] = __expf(lg[k] - mx); sum += e[k]; }
  const float inv = 1.0f / sum;

  const float* op = offs + (size_t)pix * 8;
  const u16* kb = keyn + (size_t)b * P_ * C_ + 2 * lane;
  float a0 = 0.f, a1 = 0.f;
#pragma unroll
  for (int k = 0; k < 4; k++) {
    float gx = (2.0f * w / 255.0f - 1.0f) + op[2 * k] * (1.0f / 128.0f);
    float gy = (2.0f * h / 255.0f - 1.0f) + op[2 * k + 1] * (1.0f / 128.0f);
    gx = fminf(fmaxf(gx, -1.f), 1.f);
    gy = fminf(fmaxf(gy, -1.f), 1.f);
    float px = (gx + 1.f) * 127.5f;
    float py = (gy + 1.f) * 127.5f;
    px = fminf(fmaxf(px, 0.f), 255.f);
    py = fminf(fmaxf(py, 0.f), 255.f);
    int x0 = (int)px, y0 = (int)py;            // px,py >= 0: trunc == floor
    int x1 = min(x0 + 1, 255), y1 = min(y0 + 1, 255);
    float wx = px - x0, wy = py - y0;
    unsigned int u00 = *(const unsigned int*)&kb[((size_t)(y0 * 256 + x0)) * C_];
    unsigned int u01 = *(const unsigned int*)&kb[((size_t)(y0 * 256 + x1)) * C_];
    unsigned int u10 = *(const unsigned int*)&kb[((size_t)(y1 * 256 + x0)) * C_];
    unsigned int u11 = *(const unsigned int*)&kb[((size_t)(y1 * 256 + x1)) * C_];
    float v00a = bf2f((u16)u00), v00b = bf2f((u16)(u00 >> 16));
    float v01a = bf2f((u16)u01), v01b = bf2f((u16)(u01 >> 16));
    float v10a = bf2f((u16)u10), v10b = bf2f((u16)(u10 >> 16));
    float v11a = bf2f((u16)u11), v11b = bf2f((u16)(u11 >> 16));
    float t0a = v00a + wx * (v01a - v00a);
    float t1a = v10a + wx * (v11a - v10a);
    float fa = t0a + wy * (t1a - t0a);
    float t0b = v00b + wx * (v01b - v00b);
    float t1b = v10b + wx * (v11b - v10b);
    float fb = t0b + wy * (t1b - t0b);
    float wk = e[k] * inv;
    a0 += wk * fa;
    a1 += wk * fb;
  }
  unsigned int outu = ((unsigned int)f2bf(a1) << 16) | (unsigned int)f2bf(a0);
  *(unsigned int*)&agg[(size_t)pix * C_ + 2 * lane] = outu;
}

extern "C" void kernel_launch(void* const* d_in, const int* in_sizes, int n_in,
                              void* d_out, int out_size, void* d_ws, size_t ws_size,
                              hipStream_t stream) {
  (void)in_sizes; (void)n_in; (void)out_size; (void)ws_size;
  const float* q   = (const float*)d_in[0];
  const float* key = (const float*)d_in[1];
  const float* ow1 = (const float*)d_in[2];
  const float* ob1 = (const float*)d_in[3];
  const float* ow2 = (const float*)d_in[4];
  const float* ob2 = (const float*)d_in[5];
  const float* ww1 = (const float*)d_in[6];
  const float* wb1 = (const float*)d_in[7];
  const float* ww2 = (const float*)d_in[8];
  const float* wb2 = (const float*)d_in[9];
  const float* fw1 = (const float*)d_in[10];
  const float* fb1 = (const float*)d_in[11];
  const float* fw2 = (const float*)d_in[12];
  const float* fb2 = (const float*)d_in[13];
  float* out = (float*)d_out;
  char* ws = (char*)d_ws;

  // workspace layout (bytes): total ~114.8 MB
  u16* qpad   = (u16*)(ws);                  // [2][258][258][128] bf16, 34,080,768 B (reused as t2)
  u16* t1pad  = (u16*)(ws + 34080768);       // same shape                (reused as agg)
  u16* keyn   = (u16*)(ws + 68161536);       // [2][65536][128] bf16, 33,554,432 B
  float* offs = (float*)(ws + 101715968);    // [2][65536][8] fp32,    4,194,304 B
  u16* w1b    = (u16*)(ws + 105910272);      // [2][65536][32] bf16,   8,388,608 B
  u16* wbuf   = (u16*)(ws + 114298880);      // 235520 bf16 weights,     471,040 B
  u16* t2  = qpad;
  u16* agg = t1pad;

  border_zero<<<1032, 256, 0, stream>>>(qpad);
  border_zero<<<1032, 256, 0, stream>>>(t1pad);
  repack_weights<<<920, 256, 0, stream>>>(ow1, ow2, ww1, fw1, fw2, wbuf);
  to_nhwc<<<dim3(4, 256, 4), 256, 0, stream>>>(q, qpad, HP_, WP_, 1);
  to_nhwc<<<dim3(4, 256, 4), 256, 0, stream>>>(key, keyn, H_, W_, 0);

  // offset_net conv1 (3x3 128->128) + GELU -> t1pad (padded NHWC bf16)
  gemm_conv<64, 64, 2, 2, 9, 0><<<dim3(4, 256, 4), 256, 0, stream>>>(
      qpad, wbuf, ob1, t1pad, nullptr, nullptr,
      HP_, WP_, 128, 128, HP_, WP_, 1, 128, 2);
  // offset_net conv2 (3x3 128->8) -> offs fp32
  gemm_conv<128, 16, 4, 1, 9, 1><<<dim3(2, 256, 2), 256, 0, stream>>>(
      t1pad, wbuf + 147456, ob2, nullptr, offs, nullptr,
      HP_, WP_, 16, 8, 0, 0, 0, 0, 1);
  // weight_net conv1 (3x3 128->32) + GELU -> w1b
  gemm_conv<128, 32, 2, 2, 9, 0><<<dim3(2, 256, 2), 256, 0, stream>>>(
      qpad, wbuf + 165888, wb1, w1b, nullptr, nullptr,
      HP_, WP_, 32, 32, H_, W_, 0, 32, 1);
  // logits + softmax + grid_sample + weighted sum -> agg
  sampler<<<32768, 256, 0, stream>>>(offs, w1b, ww2, wb2, keyn, agg);
  // fusion conv1 (1x1) + GELU -> t2
  gemm_conv<64, 64, 2, 2, 1, 0><<<dim3(4, 256, 4), 256, 0, stream>>>(
      agg, wbuf + 202752, fb1, t2, nullptr, nullptr,
      H_, W_, 128, 128, H_, W_, 0, 128, 2);
  // fusion conv2 (1x1) + residual -> out (NCHW fp32)
  gemm_conv<64, 64, 2, 2, 1, 2><<<dim3(4, 256, 4), 256, 0, stream>>>(
      t2, wbuf + 219136, fb2, nullptr, out, q,
      H_, W_, 128, 128, 0, 0, 0, 128, 2);
}

// Round 2
// 514.060 us; speedup vs baseline: 1.0034x; 1.0034x over previous
//
#include <hip/hip_runtime.h>

typedef unsigned short u16;
typedef __attribute__((ext_vector_type(8))) short bf16x8;
typedef __attribute__((ext_vector_type(4))) float f32x4;

constexpr int B_ = 2, C_ = 128, H_ = 256, W_ = 256, P_ = H_ * W_;
constexpr int HP_ = 258, WP_ = 258;

__device__ __forceinline__ float bf2f(u16 u) {
  union { unsigned int i; float f; } v; v.i = ((unsigned int)u) << 16; return v.f;
}
__device__ __forceinline__ u16 f2bf(float f) {
  union { float f; unsigned int i; } v; v.f = f;
  return (u16)((v.i + 0x7fffu + ((v.i >> 16) & 1u)) >> 16);  // RNE
}
__device__ __forceinline__ float gelu_f(float x) {
  return 0.5f * x * (1.0f + erff(x * 0.70710678118654752f));
}

// async global->LDS, 16B per lane. LDS dest must be wave-uniform base + lane*16.
__device__ __forceinline__ void async16(const u16* g, u16* l) {
  __builtin_amdgcn_global_load_lds(
      (const __attribute__((address_space(1))) unsigned int*)g,
      (__attribute__((address_space(3))) unsigned int*)l, 16, 0, 0);
}

// Zero the 1-px border of a [B][258][258][128] bf16 buffer. idx < 2*4*258*128.
__global__ __launch_bounds__(256) void border_zero(u16* __restrict__ buf) {
  int idx = blockIdx.x * 256 + threadIdx.x;
  int c = idx & 127;
  int t = idx >> 7;
  int pos = t % 258;
  int side = (t / 258) & 3;
  int b = t / (258 * 4);
  int h, w;
  if (side == 0) { h = 0;   w = pos; }
  else if (side == 1) { h = 257; w = pos; }
  else if (side == 2) { h = pos; w = 0; }
  else { h = pos; w = 257; }
  buf[(((size_t)b * HP_ + h) * WP_ + w) * C_ + c] = 0;
}

// NCHW fp32 -> NHWC bf16 (optionally into padded interior). 64ch x 64px tiles via LDS.
__global__ __launch_bounds__(256) void to_nhwc(const float* __restrict__ in, u16* __restrict__ out,
                                               int OHp, int OWp, int opad) {
  __shared__ u16 l[64 * 66];
  int tid = threadIdx.x;
  int b = blockIdx.z >> 1, c0 = (blockIdx.z & 1) * 64;
  int h = blockIdx.y, w0 = blockIdx.x * 64;
  for (int it = 0; it < 16; ++it) {
    int lin = it * 256 + tid;
    int c = lin >> 6, w = lin & 63;
    l[c * 66 + w] = f2bf(in[(((size_t)b * C_ + c0 + c) * H_ + h) * W_ + w0 + w]);
  }
  __syncthreads();
  for (int it = 0; it < 16; ++it) {
    int lin = it * 256 + tid;
    int w = lin >> 6, c = lin & 63;
    out[(((size_t)b * OHp + h + opad) * OWp + (w0 + w + opad)) * C_ + c0 + c] = l[c * 66 + w];
  }
}

// Repack all conv weights into bf16 [tap][co][ci] layouts, concatenated:
// W1 @0      : 9*128*128 = 147456   (ow1)
// W2 @147456 : 9*16*128  = 18432    (ow2, co padded 8->16 with zeros)
// W3 @165888 : 9*32*128  = 36864    (ww1)
// W4 @202752 : 128*128   = 16384    (fw1)
// W5 @219136 : 128*128   = 16384    (fw2)   total 235520
__global__ __launch_bounds__(256) void repack_weights(
    const float* __restrict__ ow1, const float* __restrict__ ow2,
    const float* __restrict__ ww1, const float* __restrict__ fw1,
    const float* __restrict__ fw2, u16* __restrict__ wb) {
  int idx = blockIdx.x * 256 + threadIdx.x;
  float v;
  if (idx < 147456) {
    int tap = idx / 16384, r = idx % 16384, co = r >> 7, ci = r & 127;
    v = ow1[((co * 128 + ci) * 3 + tap / 3) * 3 + tap % 3];
  } else if (idx < 165888) {
    int j = idx - 147456;
    int tap = j / 2048, r = j % 2048, co = r >> 7, ci = r & 127;
    v = (co < 8) ? ow2[((co * 128 + ci) * 3 + tap / 3) * 3 + tap % 3] : 0.0f;
  } else if (idx < 202752) {
    int j = idx - 165888;
    int tap = j / 4096, r = j % 4096, co = r >> 7, ci = r & 127;
    v = ww1[((co * 128 + ci) * 3 + tap / 3) * 3 + tap % 3];
  } else if (idx < 219136) {
    v = fw1[idx - 202752];
  } else {
    v = fw2[idx - 219136];
  }
  wb[idx] = f2bf(v);
}

// Implicit-GEMM conv, m97-style: BK=64, global_load_lds(16B) staging, XOR-swizzled LDS.
// A: NHWC bf16 (padded if NTAPS==9). Wt: [tap][co][ci] bf16 (co range = CoutPad = BN).
// M = BM pixels along w (fixed h), N = BN output channels, K = NTAPS*128.
// LDS layout: row-major [row][64], 16B block cb holds logical k-block (cb ^ (row&7)).
// EPI 0: GELU -> bf16 NHWC (opad, stride OC into [OHp][OWp])
// EPI 1: fp32 -> [b][p][CoutStore], only co < CoutStore
// EPI 2: fp32 NCHW residual: out = resid + 0.3*(acc+bias), float4 stores along w
template <int BM, int BN, int WR, int WC, int NTAPS, int EPI>
__global__ __launch_bounds__(256) void gemm_conv(
    const u16* __restrict__ A, const u16* __restrict__ Wt,
    const float* __restrict__ bias,
    u16* __restrict__ outb, float* __restrict__ outf,
    const float* __restrict__ resid,
    int Hp, int Wp, int CoutPad, int CoutStore,
    int OHp, int OWp, int opad, int OC) {
  constexpr int TM = BM / WR / 16, TN = BN / WC / 16;
  __shared__ __align__(16) u16 As[BM * 64];
  __shared__ __align__(16) u16 Bs[BN * 64];
  const int tid = threadIdx.x, lane = tid & 63, wave = tid >> 6;
  const int h = blockIdx.y, w0 = blockIdx.x * BM;
  const int b = blockIdx.z;
  const int wr = wave / WC, wc = wave % WC;
  const int wm = wr * (BM / WR), wn = wc * (BN / WC);
  const int lr = lane & 15;
  const int sw = (lr & 7);  // fragment-row swizzle key (row%8 == lr%8)

  f32x4 acc[TM][TN];
#pragma unroll
  for (int i = 0; i < TM; i++)
#pragma unroll
    for (int j = 0; j < TN; j++) { f32x4 z = {0.f, 0.f, 0.f, 0.f}; acc[i][j] = z; }

  for (int c = 0; c < NTAPS * 2; ++c) {
    const int tap = c >> 1, ci0 = (c & 1) << 6;
    const int ky = (NTAPS == 9) ? tap / 3 : 0;
    const int kx = (NTAPS == 9) ? tap % 3 : 0;
    const u16* Ab = A + (((size_t)b * Hp + h + ky) * Wp + (w0 + kx)) * 128 + ci0;
    const u16* Wb = Wt + ((size_t)tap * CoutPad) * 128 + ci0;
    __syncthreads();
    for (int i = tid; i < BM * 8; i += 256) {
      int r = i >> 3, cb = i & 7;
      async16(Ab + r * 128 + ((cb ^ (r & 7)) << 3), As + i * 8);
    }
    for (int i = tid; i < BN * 8; i += 256) {
      int r = i >> 3, cb = i & 7;
      async16(Wb + r * 128 + ((cb ^ (r & 7)) << 3), Bs + i * 8);
    }
    __syncthreads();
#pragma unroll
    for (int ks = 0; ks < 2; ++ks) {
      const int kb = ks * 4 + (lane >> 4);
      bf16x8 af[TM], bfr[TN];
#pragma unroll
      for (int i = 0; i < TM; i++)
        af[i] = *(const bf16x8*)&As[(wm + i * 16 + lr) * 64 + ((kb ^ sw) << 3)];
#pragma unroll
      for (int j = 0; j < TN; j++)
        bfr[j] = *(const bf16x8*)&Bs[(wn + j * 16 + lr) * 64 + ((kb ^ sw) << 3)];
#pragma unroll
      for (int i = 0; i < TM; i++)
#pragma unroll
        for (int j = 0; j < TN; j++)
          acc[i][j] = __builtin_amdgcn_mfma_f32_16x16x32_bf16(af[i], bfr[j], acc[i][j], 0, 0, 0);
    }
  }

#pragma unroll
  for (int i = 0; i < TM; i++) {
#pragma unroll
    for (int j = 0; j < TN; j++) {
      const int co = wn + j * 16 + lr;
      if (EPI == 2) {
        const int w = w0 + wm + i * 16 + (lane >> 4) * 4;
        size_t idx = ((size_t)b * OC + co) * (size_t)P_ + (size_t)h * W_ + w;
        float4 rv = *(const float4*)&resid[idx];
        float bi = bias[co];
        float4 ov;
        ov.x = rv.x + 0.3f * (acc[i][j][0] + bi);
        ov.y = rv.y + 0.3f * (acc[i][j][1] + bi);
        ov.z = rv.z + 0.3f * (acc[i][j][2] + bi);
        ov.w = rv.w + 0.3f * (acc[i][j][3] + bi);
        *(float4*)&outf[idx] = ov;
      } else {
#pragma unroll
        for (int r = 0; r < 4; r++) {
          const int w = w0 + wm + i * 16 + (lane >> 4) * 4 + r;
          float v = acc[i][j][r];
          if (EPI == 0) {
            v = gelu_f(v + bias[co]);
            outb[(((size_t)b * OHp + h + opad) * OWp + (w + opad)) * OC + co] = f2bf(v);
          } else {
            if (co < CoutStore)
              outf[((size_t)b * P_ + (size_t)h * W_ + w) * CoutStore + co] = v + bias[co];
          }
        }
      }
    }
  }
}

// Per-pixel: 1x1 conv 32->4 logits, softmax, 4x bilinear grid_sample over 128ch, weighted sum.
// One wave per pixel; lane handles channel pair (2*lane, 2*lane+1). Corner loads are
// coalesced: 64 lanes read consecutive dwords of one pixel's 256B channel vector.
__global__ __launch_bounds__(256) void sampler(
    const float* __restrict__ offs, const u16* __restrict__ w1,
    const float* __restrict__ ww2, const float* __restrict__ wb2,
    const u16* __restrict__ keyn, u16* __restrict__ agg) {
  const int tid = threadIdx.x, lane = tid & 63, wv = tid >> 6;
  const int pix = blockIdx.x * 4 + wv;
  const int b = pix >> 16, p = pix & 65535;
  const int h = p >> 8, w = p & 255;

  const u16* w1p = w1 + (size_t)pix * 32;
  float lg[4];
#pragma unroll
  for (int k = 0; k < 4; k++) {
    float s = wb2[k];
#pragma unroll
    for (int i = 0; i < 32; i++) s += ww2[k * 32 + i] * bf2f(w1p[i]);
    lg[k] = s;
  }
  float mx = fmaxf(fmaxf(lg[0], lg[1]), fmaxf(lg[2], lg[3]));
  float e[4]; float sum = 0.f;
#pragma unroll
  for (int k = 0; k < 4; k++) { e[k] = __expf(lg[k] - mx); sum += e[k]; }
  const float inv = 1.0f / sum;

  const float* op = offs + (size_t)pix * 8;
  const u16* kb = keyn + (size_t)b * P_ * C_ + 2 * lane;
  float a0 = 0.f, a1 = 0.f;
#pragma unroll
  for (int k = 0; k < 4; k++) {
    float gx = (2.0f * w / 255.0f - 1.0f) + op[2 * k] * (1.0f / 128.0f);
    float gy = (2.0f * h / 255.0f - 1.0f) + op[2 * k + 1] * (1.0f / 128.0f);
    gx = fminf(fmaxf(gx, -1.f), 1.f);
    gy = fminf(fmaxf(gy, -1.f), 1.f);
    float px = (gx + 1.f) * 127.5f;
    float py = (gy + 1.f) * 127.5f;
    px = fminf(fmaxf(px, 0.f), 255.f);
    py = fminf(fmaxf(py, 0.f), 255.f);
    int x0 = (int)px, y0 = (int)py;            // px,py >= 0: trunc == floor
    int x1 = min(x0 + 1, 255), y1 = min(y0 + 1, 255);
    float wx = px - x0, wy = py - y0;
    unsigned int u00 = *(const unsigned int*)&kb[((size_t)(y0 * 256 + x0)) * C_];
    unsigned int u01 = *(const unsigned int*)&kb[((size_t)(y0 * 256 + x1)) * C_];
    unsigned int u10 = *(const unsigned int*)&kb[((size_t)(y1 * 256 + x0)) * C_];
    unsigned int u11 = *(const unsigned int*)&kb[((size_t)(y1 * 256 + x1)) * C_];
    float v00a = bf2f((u16)u00), v00b = bf2f((u16)(u00 >> 16));
    float v01a = bf2f((u16)u01), v01b = bf2f((u16)(u01 >> 16));
    float v10a = bf2f((u16)u10), v10b = bf2f((u16)(u10 >> 16));
    float v11a = bf2f((u16)u11), v11b = bf2f((u16)(u11 >> 16));
    float t0a = v00a + wx * (v01a - v00a);
    float t1a = v10a + wx * (v11a - v10a);
    float fa = t0a + wy * (t1a - t0a);
    float t0b = v00b + wx * (v01b - v00b);
    float t1b = v10b + wx * (v11b - v10b);
    float fb = t0b + wy * (t1b - t0b);
    float wk = e[k] * inv;
    a0 += wk * fa;
    a1 += wk * fb;
  }
  unsigned int outu = ((unsigned int)f2bf(a1) << 16) | (unsigned int)f2bf(a0);
  *(unsigned int*)&agg[(size_t)pix * C_ + 2 * lane] = outu;
}

extern "C" void kernel_launch(void* const* d_in, const int* in_sizes, int n_in,
                              void* d_out, int out_size, void* d_ws, size_t ws_size,
                              hipStream_t stream) {
  (void)in_sizes; (void)n_in; (void)out_size; (void)ws_size;
  const float* q   = (const float*)d_in[0];
  const float* key = (const float*)d_in[1];
  const float* ow1 = (const float*)d_in[2];
  const float* ob1 = (const float*)d_in[3];
  const float* ow2 = (const float*)d_in[4];
  const float* ob2 = (const float*)d_in[5];
  const float* ww1 = (const float*)d_in[6];
  const float* wb1 = (const float*)d_in[7];
  const float* ww2 = (const float*)d_in[8];
  const float* wb2 = (const float*)d_in[9];
  const float* fw1 = (const float*)d_in[10];
  const float* fb1 = (const float*)d_in[11];
  const float* fw2 = (const float*)d_in[12];
  const float* fb2 = (const float*)d_in[13];
  float* out = (float*)d_out;
  char* ws = (char*)d_ws;

  // workspace layout (bytes): total ~114.8 MB
  u16* qpad   = (u16*)(ws);                  // [2][258][258][128] bf16, 34,080,768 B (reused as t2)
  u16* t1pad  = (u16*)(ws + 34080768);       // same shape                (reused as agg)
  u16* keyn   = (u16*)(ws + 68161536);       // [2][65536][128] bf16, 33,554,432 B
  float* offs = (float*)(ws + 101715968);    // [2][65536][8] fp32,    4,194,304 B
  u16* w1b    = (u16*)(ws + 105910272);      // [2][65536][32] bf16,   8,388,608 B
  u16* wbuf   = (u16*)(ws + 114298880);      // 235520 bf16 weights,     471,040 B
  u16* t2  = qpad;
  u16* agg = t1pad;

  border_zero<<<1032, 256, 0, stream>>>(qpad);
  border_zero<<<1032, 256, 0, stream>>>(t1pad);
  repack_weights<<<920, 256, 0, stream>>>(ow1, ow2, ww1, fw1, fw2, wbuf);
  to_nhwc<<<dim3(4, 256, 4), 256, 0, stream>>>(q, qpad, HP_, WP_, 1);
  to_nhwc<<<dim3(4, 256, 4), 256, 0, stream>>>(key, keyn, H_, W_, 0);

  // offset_net conv1 (3x3 128->128) + GELU -> t1pad (padded NHWC bf16)
  gemm_conv<128, 128, 2, 2, 9, 0><<<dim3(2, 256, 2), 256, 0, stream>>>(
      qpad, wbuf, ob1, t1pad, nullptr, nullptr,
      HP_, WP_, 128, 128, HP_, WP_, 1, 128);
  // offset_net conv2 (3x3 128->8) -> offs fp32
  gemm_conv<256, 16, 4, 1, 9, 1><<<dim3(1, 256, 2), 256, 0, stream>>>(
      t1pad, wbuf + 147456, ob2, nullptr, offs, nullptr,
      HP_, WP_, 16, 8, 0, 0, 0, 0);
  // weight_net conv1 (3x3 128->32) + GELU -> w1b
  gemm_conv<256, 32, 4, 1, 9, 0><<<dim3(1, 256, 2), 256, 0, stream>>>(
      qpad, wbuf + 165888, wb1, w1b, nullptr, nullptr,
      HP_, WP_, 32, 32, H_, W_, 0, 32);
  // logits + softmax + grid_sample + weighted sum -> agg
  sampler<<<32768, 256, 0, stream>>>(offs, w1b, ww2, wb2, keyn, agg);
  // fusion conv1 (1x1) + GELU -> t2
  gemm_conv<128, 128, 2, 2, 1, 0><<<dim3(2, 256, 2), 256, 0, stream>>>(
      agg, wbuf + 202752, fb1, t2, nullptr, nullptr,
      H_, W_, 128, 128, H_, W_, 0, 128);
  // fusion conv2 (1x1) + residual -> out (NCHW fp32)
  gemm_conv<128, 128, 2, 2, 1, 2><<<dim3(2, 256, 2), 256, 0, stream>>>(
      t2, wbuf + 219136, fb2, nullptr, out, q,
      H_, W_, 128, 128, 0, 0, 0, 128);
}

// Round 3
// 459.699 us; speedup vs baseline: 1.1221x; 1.1183x over previous
//
#include <hip/hip_runtime.h>
#include <hip/hip_fp16.h>

typedef unsigned short u16;
typedef __attribute__((ext_vector_type(8))) short bf16x8;
typedef __attribute__((ext_vector_type(4))) float f32x4;

constexpr int B_ = 2, C_ = 128, H_ = 256, W_ = 256, P_ = H_ * W_;
constexpr int HP_ = 258, WP_ = 258;

union HU { __half2 h; unsigned int u; };

__device__ __forceinline__ float bf2f(u16 u) {
  union { unsigned int i; float f; } v; v.i = ((unsigned int)u) << 16; return v.f;
}
__device__ __forceinline__ u16 f2bf(float f) {
  union { float f; unsigned int i; } v; v.f = f;
  return (u16)((v.i + 0x7fffu + ((v.i >> 16) & 1u)) >> 16);  // RNE
}
__device__ __forceinline__ float gelu_f(float x) {
  return 0.5f * x * (1.0f + erff(x * 0.70710678118654752f));
}

// async global->LDS, 16B per lane. LDS dest must be wave-uniform base + lane*16.
__device__ __forceinline__ void async16(const u16* g, u16* l) {
  __builtin_amdgcn_global_load_lds(
      (const __attribute__((address_space(1))) unsigned int*)g,
      (__attribute__((address_space(3))) unsigned int*)l, 16, 0, 0);
}

// Zero the 1-px border of a [B][258][258][128] bf16 buffer. idx < 2*4*258*128.
__global__ __launch_bounds__(256) void border_zero(u16* __restrict__ buf) {
  int idx = blockIdx.x * 256 + threadIdx.x;
  int c = idx & 127;
  int t = idx >> 7;
  int pos = t % 258;
  int side = (t / 258) & 3;
  int b = t / (258 * 4);
  int h, w;
  if (side == 0) { h = 0;   w = pos; }
  else if (side == 1) { h = 257; w = pos; }
  else if (side == 2) { h = pos; w = 0; }
  else { h = pos; w = 257; }
  buf[(((size_t)b * HP_ + h) * WP_ + w) * C_ + c] = 0;
}

// NCHW fp32 -> NHWC bf16 (optionally into padded interior). 64ch x 64px tiles via LDS.
__global__ __launch_bounds__(256) void to_nhwc(const float* __restrict__ in, u16* __restrict__ out,
                                               int OHp, int OWp, int opad) {
  __shared__ u16 l[64 * 66];
  int tid = threadIdx.x;
  int b = blockIdx.z >> 1, c0 = (blockIdx.z & 1) * 64;
  int h = blockIdx.y, w0 = blockIdx.x * 64;
  for (int it = 0; it < 16; ++it) {
    int lin = it * 256 + tid;
    int c = lin >> 6, w = lin & 63;
    l[c * 66 + w] = f2bf(in[(((size_t)b * C_ + c0 + c) * H_ + h) * W_ + w0 + w]);
  }
  __syncthreads();
  for (int it = 0; it < 16; ++it) {
    int lin = it * 256 + tid;
    int w = lin >> 6, c = lin & 63;
    out[(((size_t)b * OHp + h + opad) * OWp + (w0 + w + opad)) * C_ + c0 + c] = l[c * 66 + w];
  }
}

// Repack conv weights, bf16, concatenated into wbuf:
// 3x3 convs fragment-packed: [tap][ciq 4][g][kb 4][lr 16][e 8]  (ci = ciq*32+kb*8+e, co = g*16+lr)
//   ow1 @0      : 147456 (G=8)
//   ow2 @147456 : 18432  (G=1, co 8->16 zero-pad)
//   ww1 @165888 : 36864  (G=2)
// 1x1 convs row-major [co][ci]:
//   fw1 @202752 : 16384
//   fw2 @219136 : 16384      total 235520
__global__ __launch_bounds__(256) void repack_weights(
    const float* __restrict__ ow1, const float* __restrict__ ow2,
    const float* __restrict__ ww1, const float* __restrict__ fw1,
    const float* __restrict__ fw2, u16* __restrict__ wb) {
  int idx = blockIdx.x * 256 + threadIdx.x;
  float v;
  if (idx < 147456) {
    int e = idx & 7, lr = (idx >> 3) & 15, kb = (idx >> 7) & 3;
    int g = (idx >> 9) & 7, cq = (idx >> 12) & 3, tap = idx >> 14;
    int ci = cq * 32 + kb * 8 + e, co = g * 16 + lr;
    v = ow1[(co * 128 + ci) * 9 + tap];
  } else if (idx < 165888) {
    int j = idx - 147456;
    int e = j & 7, lr = (j >> 3) & 15, kb = (j >> 7) & 3;
    int cq = (j >> 9) & 3, tap = j >> 11;
    int ci = cq * 32 + kb * 8 + e, co = lr;
    v = (co < 8) ? ow2[(co * 128 + ci) * 9 + tap] : 0.0f;
  } else if (idx < 202752) {
    int j = idx - 165888;
    int e = j & 7, lr = (j >> 3) & 15, kb = (j >> 7) & 3;
    int g = (j >> 9) & 1, cq = (j >> 10) & 3, tap = j >> 12;
    int ci = cq * 32 + kb * 8 + e, co = g * 16 + lr;
    v = ww1[(co * 128 + ci) * 9 + tap];
  } else if (idx < 219136) {
    v = fw1[idx - 202752];
  } else {
    v = fw2[idx - 219136];
  }
  wb[idx] = f2bf(v);
}

// 3x3 implicit-GEMM conv with 3-row LDS staging (A staged ONCE per ci-quarter, all 9
// taps consume it) and B fragments loaded directly from global (fragment-packed, L2-hot).
// A: padded NHWC bf16 [b][Hp][Wp][128]. Output row h uses padded rows h..h+2.
// LDS As[3][RP][32ci], 16B chunks XOR-swizzled by (px>>1)&3 -> 2-way conflicts only (free).
// GT = total co groups (Cout_total/16) in Wf; NT = #BN tiles in z.
// EPI 0: GELU -> bf16 NHWC [b][OHp][OWp][OC] interior opad
// EPI 1: +bias fp32 -> [b][p][CoutStore], only co < CoutStore
template <int BM, int BN, int WR, int WC, int NT, int GT, int EPI>
__global__ __launch_bounds__(256) void gemm_conv3(
    const u16* __restrict__ A, const u16* __restrict__ Wf,
    const float* __restrict__ bias,
    u16* __restrict__ outb, float* __restrict__ outf,
    int Hp, int Wp, int OHp, int OWp, int opad, int OC, int CoutStore) {
  constexpr int TM = BM / WR / 16, TN = BN / WC / 16;
  constexpr int RP = BM + 16;       // row pitch in px; RP*4 chunks/row (mult of 64)
  constexpr int CHR = RP * 4;
  __shared__ __align__(16) u16 As[3 * RP * 32];
  const int tid = threadIdx.x, lane = tid & 63, wave = tid >> 6;
  const int h = blockIdx.y, w0 = blockIdx.x * BM;
  const int b = blockIdx.z / NT, n0 = (blockIdx.z % NT) * BN;
  const int wm = (wave / WC) * (BM / WR), wn = (wave % WC) * (BN / WC);
  const int lr = lane & 15, kq = lane >> 4;
  const int gbase = (n0 >> 4) + (wn >> 4);

  // A-fragment LDS byte offsets (within one ky plane), per (i, kx)
  int preA[TM][3];
#pragma unroll
  for (int i = 0; i < TM; i++)
#pragma unroll
    for (int kx = 0; kx < 3; kx++) {
      int row = wm + i * 16 + lr + kx;
      preA[i][kx] = row * 64 + (((kq ^ (row >> 1)) & 3) << 4);
    }

  f32x4 acc[TM][TN];
#pragma unroll
  for (int i = 0; i < TM; i++)
#pragma unroll
    for (int j = 0; j < TN; j++) { f32x4 z = {0.f, 0.f, 0.f, 0.f}; acc[i][j] = z; }

  const size_t rowpx = ((size_t)b * Hp + h) * Wp + w0;
  for (int cq = 0; cq < 4; ++cq) {
    const int ci0 = cq * 32;
    __syncthreads();
    for (int i = tid; i < 3 * CHR; i += 256) {
      int ky = i / CHR;
      int rem = i - ky * CHR;
      int px = rem >> 2, cb = rem & 3;
      async16(A + (rowpx + (size_t)ky * Wp + px) * 128 + ci0 + (((cb ^ (px >> 1)) & 3) << 3),
              As + i * 8);
    }
    __syncthreads();
#pragma unroll
    for (int tap = 0; tap < 9; ++tap) {
      const int ky = tap / 3, kx = tap % 3;
      bf16x8 bfr[TN], af[TM];
#pragma unroll
      for (int j = 0; j < TN; ++j)
        bfr[j] = *(const bf16x8*)&Wf[(size_t)((((tap * 4 + cq) * GT + gbase + j) * 4 + kq) * 16 + lr) * 8];
#pragma unroll
      for (int i = 0; i < TM; ++i)
        af[i] = *(const bf16x8*)((const char*)As + ky * (RP * 64) + preA[i][kx]);
#pragma unroll
      for (int i = 0; i < TM; i++)
#pragma unroll
        for (int j = 0; j < TN; j++)
          acc[i][j] = __builtin_amdgcn_mfma_f32_16x16x32_bf16(af[i], bfr[j], acc[i][j], 0, 0, 0);
    }
  }

#pragma unroll
  for (int i = 0; i < TM; i++) {
#pragma unroll
    for (int j = 0; j < TN; j++) {
      const int co = n0 + wn + j * 16 + lr;
#pragma unroll
      for (int r = 0; r < 4; r++) {
        const int w = w0 + wm + i * 16 + (lane >> 4) * 4 + r;
        float v = acc[i][j][r];
        if (EPI == 0) {
          v = gelu_f(v + bias[co]);
          outb[(((size_t)b * OHp + h + opad) * OWp + (w + opad)) * OC + co] = f2bf(v);
        } else {
          if (co < CoutStore)
            outf[((size_t)b * P_ + (size_t)h * W_ + w) * CoutStore + co] = v + bias[co];
        }
      }
    }
  }
}

// 1x1 implicit-GEMM (fusion convs), m97-style LDS staging for A and B. BK=64.
// EPI 0: GELU -> bf16 [b][OHp][OWp][OC]; EPI 2: fp32 NCHW residual out = resid + 0.3*(acc+bias)
template <int BM, int BN, int WR, int WC, int EPI>
__global__ __launch_bounds__(256) void gemm_conv(
    const u16* __restrict__ A, const u16* __restrict__ Wt,
    const float* __restrict__ bias,
    u16* __restrict__ outb, float* __restrict__ outf,
    const float* __restrict__ resid,
    int Hp, int Wp, int OHp, int OWp, int opad, int OC) {
  constexpr int TM = BM / WR / 16, TN = BN / WC / 16;
  __shared__ __align__(16) u16 As[BM * 64];
  __shared__ __align__(16) u16 Bs[BN * 64];
  const int tid = threadIdx.x, lane = tid & 63, wave = tid >> 6;
  const int h = blockIdx.y, w0 = blockIdx.x * BM;
  const int b = blockIdx.z;
  const int wr = wave / WC, wc = wave % WC;
  const int wm = wr * (BM / WR), wn = wc * (BN / WC);
  const int lr = lane & 15;
  const int sw = (lr & 7);

  f32x4 acc[TM][TN];
#pragma unroll
  for (int i = 0; i < TM; i++)
#pragma unroll
    for (int j = 0; j < TN; j++) { f32x4 z = {0.f, 0.f, 0.f, 0.f}; acc[i][j] = z; }

  for (int c = 0; c < 2; ++c) {
    const int ci0 = c << 6;
    const u16* Ab = A + (((size_t)b * Hp + h) * Wp + w0) * 128 + ci0;
    const u16* Wb = Wt + ci0;
    __syncthreads();
    for (int i = tid; i < BM * 8; i += 256) {
      int r = i >> 3, cb = i & 7;
      async16(Ab + r * 128 + ((cb ^ (r & 7)) << 3), As + i * 8);
    }
    for (int i = tid; i < BN * 8; i += 256) {
      int r = i >> 3, cb = i & 7;
      async16(Wb + r * 128 + ((cb ^ (r & 7)) << 3), Bs + i * 8);
    }
    __syncthreads();
#pragma unroll
    for (int ks = 0; ks < 2; ++ks) {
      const int kb = ks * 4 + (lane >> 4);
      bf16x8 af[TM], bfr[TN];
#pragma unroll
      for (int i = 0; i < TM; i++)
        af[i] = *(const bf16x8*)&As[(wm + i * 16 + lr) * 64 + ((kb ^ sw) << 3)];
#pragma unroll
      for (int j = 0; j < TN; j++)
        bfr[j] = *(const bf16x8*)&Bs[(wn + j * 16 + lr) * 64 + ((kb ^ sw) << 3)];
#pragma unroll
      for (int i = 0; i < TM; i++)
#pragma unroll
        for (int j = 0; j < TN; j++)
          acc[i][j] = __builtin_amdgcn_mfma_f32_16x16x32_bf16(af[i], bfr[j], acc[i][j], 0, 0, 0);
    }
  }

#pragma unroll
  for (int i = 0; i < TM; i++) {
#pragma unroll
    for (int j = 0; j < TN; j++) {
      const int co = wn + j * 16 + lr;
      if (EPI == 2) {
        const int w = w0 + wm + i * 16 + (lane >> 4) * 4;
        size_t idx = ((size_t)b * OC + co) * (size_t)P_ + (size_t)h * W_ + w;
        float4 rv = *(const float4*)&resid[idx];
        float bi = bias[co];
        float4 ov;
        ov.x = rv.x + 0.3f * (acc[i][j][0] + bi);
        ov.y = rv.y + 0.3f * (acc[i][j][1] + bi);
        ov.z = rv.z + 0.3f * (acc[i][j][2] + bi);
        ov.w = rv.w + 0.3f * (acc[i][j][3] + bi);
        *(float4*)&outf[idx] = ov;
      } else {
#pragma unroll
        for (int r = 0; r < 4; r++) {
          const int w = w0 + wm + i * 16 + (lane >> 4) * 4 + r;
          float v = gelu_f(acc[i][j][r] + bias[co]);
          outb[(((size_t)b * OHp + h + opad) * OWp + (w + opad)) * OC + co] = f2bf(v);
        }
      }
    }
  }
}

// Per-pixel prep (lane-parallel): logits = 1x1 conv 32->4, softmax, grid math.
// Emits per (pix,k) descriptor: {base|dx<<16|dy<<17, half2(w00,w01), half2(w10,w11), 0}.
__global__ __launch_bounds__(256) void prep(
    const float* __restrict__ offs, const u16* __restrict__ w1,
    const float* __restrict__ ww2, const float* __restrict__ wb2,
    uint4* __restrict__ desc) {
  const int pix = blockIdx.x * 256 + threadIdx.x;
  const int p = pix & 65535, h = p >> 8, w = p & 255;
  const u16* wp = w1 + (size_t)pix * 32;
  float f[32];
#pragma unroll
  for (int i = 0; i < 32; i += 2) {
    unsigned int u = *(const unsigned int*)&wp[i];
    f[i] = bf2f((u16)u); f[i + 1] = bf2f((u16)(u >> 16));
  }
  float lg[4];
#pragma unroll
  for (int k = 0; k < 4; k++) {
    float s = wb2[k];
#pragma unroll
    for (int i = 0; i < 32; i++) s = fmaf(ww2[k * 32 + i], f[i], s);
    lg[k] = s;
  }
  float mx = fmaxf(fmaxf(lg[0], lg[1]), fmaxf(lg[2], lg[3]));
  float e[4], sum = 0.f;
#pragma unroll
  for (int k = 0; k < 4; k++) { e[k] = __expf(lg[k] - mx); sum += e[k]; }
  const float inv = 1.0f / sum;

  const float* op = offs + (size_t)pix * 8;
#pragma unroll
  for (int k = 0; k < 4; k++) {
    float gx = (2.0f * w / 255.0f - 1.0f) + op[2 * k] * (1.0f / 128.0f);
    float gy = (2.0f * h / 255.0f - 1.0f) + op[2 * k + 1] * (1.0f / 128.0f);
    gx = fminf(fmaxf(gx, -1.f), 1.f);
    gy = fminf(fmaxf(gy, -1.f), 1.f);
    float px = fminf(fmaxf((gx + 1.f) * 127.5f, 0.f), 255.f);
    float py = fminf(fmaxf((gy + 1.f) * 127.5f, 0.f), 255.f);
    int x0 = (int)px, y0 = (int)py;          // >= 0: trunc == floor
    int x1 = min(x0 + 1, 255), y1 = min(y0 + 1, 255);
    float wx = px - x0, wy = py - y0;
    float wk = e[k] * inv;
    float w00 = (1.f - wx) * (1.f - wy) * wk, w01 = wx * (1.f - wy) * wk;
    float w10 = (1.f - wx) * wy * wk,         w11 = wx * wy * wk;
    HU t01, t23;
    t01.h = __floats2half2_rn(w00, w01);
    t23.h = __floats2half2_rn(w10, w11);
    uint4 d;
    d.x = (unsigned)(y0 * 256 + x0) | ((unsigned)(x1 - x0) << 16) | ((unsigned)(y1 - y0) << 17);
    d.y = t01.u; d.z = t23.u; d.w = 0;
    desc[(size_t)pix * 4 + k] = d;
  }
}

// Lean sampler: wave per pixel, lane = channel pair. 16 gathers + 16 FMA per lane.
__global__ __launch_bounds__(256) void sampler(
    const uint4* __restrict__ desc, const u16* __restrict__ keyn, u16* __restrict__ agg) {
  const int tid = threadIdx.x, lane = tid & 63, wv = tid >> 6;
  const int pix = blockIdx.x * 4 + wv;
  const int b = pix >> 16;
  const u16* kb = keyn + (size_t)b * (P_ * C_) + 2 * lane;
  float a0 = 0.f, a1 = 0.f;
#pragma unroll
  for (int k = 0; k < 4; ++k) {
    uint4 d = desc[(size_t)pix * 4 + k];
    const int boff = (int)(d.x & 0xFFFFu) << 7;
    const int o01 = (int)((d.x >> 16) & 1u) << 7;
    const int o10 = (int)((d.x >> 17) & 1u) << 15;
    const u16* c0 = kb + boff;
    unsigned u00 = *(const unsigned*)(c0);
    unsigned u01 = *(const unsigned*)(c0 + o01);
    unsigned u10 = *(const unsigned*)(c0 + o10);
    unsigned u11 = *(const unsigned*)(c0 + o10 + o01);
    HU t01, t23; t01.u = d.y; t23.u = d.z;
    float2 wA = __half22float2(t01.h);
    float2 wB = __half22float2(t23.h);
    a0 = fmaf(wA.x, bf2f((u16)u00), a0);
    a0 = fmaf(wA.y, bf2f((u16)u01), a0);
    a0 = fmaf(wB.x, bf2f((u16)u10), a0);
    a0 = fmaf(wB.y, bf2f((u16)u11), a0);
    a1 = fmaf(wA.x, bf2f((u16)(u00 >> 16)), a1);
    a1 = fmaf(wA.y, bf2f((u16)(u01 >> 16)), a1);
    a1 = fmaf(wB.x, bf2f((u16)(u10 >> 16)), a1);
    a1 = fmaf(wB.y, bf2f((u16)(u11 >> 16)), a1);
  }
  unsigned outu = ((unsigned)f2bf(a1) << 16) | (unsigned)f2bf(a0);
  *(unsigned*)&agg[(size_t)pix * C_ + 2 * lane] = outu;
}

extern "C" void kernel_launch(void* const* d_in, const int* in_sizes, int n_in,
                              void* d_out, int out_size, void* d_ws, size_t ws_size,
                              hipStream_t stream) {
  (void)in_sizes; (void)n_in; (void)out_size; (void)ws_size;
  const float* q   = (const float*)d_in[0];
  const float* key = (const float*)d_in[1];
  const float* ow1 = (const float*)d_in[2];
  const float* ob1 = (const float*)d_in[3];
  const float* ow2 = (const float*)d_in[4];
  const float* ob2 = (const float*)d_in[5];
  const float* ww1 = (const float*)d_in[6];
  const float* wb1 = (const float*)d_in[7];
  const float* ww2 = (const float*)d_in[8];
  const float* wb2 = (const float*)d_in[9];
  const float* fw1 = (const float*)d_in[10];
  const float* fb1 = (const float*)d_in[11];
  const float* fw2 = (const float*)d_in[12];
  const float* fb2 = (const float*)d_in[13];
  float* out = (float*)d_out;
  char* ws = (char*)d_ws;

  // workspace layout (bytes): total ~114.8 MB
  u16* qpad   = (u16*)(ws);                  // [2][258][258][128] bf16, 34,080,768 B
  u16* t1pad  = (u16*)(ws + 34080768);       // same shape (reused as agg after conv2)
  u16* keyn   = (u16*)(ws + 68161536);       // [2][65536][128] bf16, 33,554,432 B
  float* offs = (float*)(ws + 101715968);    // [2][65536][8] fp32,    4,194,304 B
  u16* w1b    = (u16*)(ws + 105910272);      // [2][65536][32] bf16,   8,388,608 B
  u16* wbuf   = (u16*)(ws + 114298880);      // 235520 bf16 weights,     471,040 B
  u16* t2  = qpad;                           // fusion temp [2][65536][128] bf16 (16.8 MB)
  u16* agg = t1pad;
  // desc lives in qpad region past t2's extent (qpad fully consumed before prep runs)
  uint4* desc = (uint4*)(ws + 16777216);     // [2*65536][4] x 16B = 8,388,608 B

  border_zero<<<1032, 256, 0, stream>>>(qpad);
  border_zero<<<1032, 256, 0, stream>>>(t1pad);
  repack_weights<<<920, 256, 0, stream>>>(ow1, ow2, ww1, fw1, fw2, wbuf);
  to_nhwc<<<dim3(4, 256, 4), 256, 0, stream>>>(q, qpad, HP_, WP_, 1);
  to_nhwc<<<dim3(4, 256, 4), 256, 0, stream>>>(key, keyn, H_, W_, 0);

  // offset_net conv1 (3x3 128->128) + GELU -> t1pad (padded NHWC bf16)
  gemm_conv3<128, 64, 2, 2, 2, 8, 0><<<dim3(2, 256, 4), 256, 0, stream>>>(
      qpad, wbuf, ob1, t1pad, nullptr, HP_, WP_, HP_, WP_, 1, 128, 0);
  // offset_net conv2 (3x3 128->8) -> offs fp32
  gemm_conv3<128, 16, 4, 1, 1, 1, 1><<<dim3(2, 256, 2), 256, 0, stream>>>(
      t1pad, wbuf + 147456, ob2, nullptr, offs, HP_, WP_, 0, 0, 0, 0, 8);
  // weight_net conv1 (3x3 128->32) + GELU -> w1b
  gemm_conv3<128, 32, 4, 1, 1, 2, 0><<<dim3(2, 256, 2), 256, 0, stream>>>(
      qpad, wbuf + 165888, wb1, w1b, nullptr, HP_, WP_, H_, W_, 0, 32, 0);
  // logits + softmax + grid math -> descriptors
  prep<<<512, 256, 0, stream>>>(offs, w1b, ww2, wb2, desc);
  // gather + weighted sum -> agg
  sampler<<<32768, 256, 0, stream>>>(desc, keyn, agg);
  // fusion conv1 (1x1) + GELU -> t2
  gemm_conv<128, 128, 2, 2, 0><<<dim3(2, 256, 2), 256, 0, stream>>>(
      agg, wbuf + 202752, fb1, t2, nullptr, nullptr,
      H_, W_, H_, W_, 0, 128);
  // fusion conv2 (1x1) + residual -> out (NCHW fp32)
  gemm_conv<128, 128, 2, 2, 2><<<dim3(2, 256, 2), 256, 0, stream>>>(
      t2, wbuf + 219136, fb2, nullptr, out, q,
      H_, W_, 0, 0, 0, 128);
}

// Round 4
// 397.532 us; speedup vs baseline: 1.2976x; 1.1564x over previous
//
#include <hip/hip_runtime.h>
#include <hip/hip_fp16.h>

typedef unsigned short u16;
typedef __attribute__((ext_vector_type(8))) short bf16x8;
typedef __attribute__((ext_vector_type(4))) float f32x4;

constexpr int B_ = 2, C_ = 128, H_ = 256, W_ = 256, P_ = H_ * W_;
constexpr int HP_ = 258, WP_ = 258;

union HU { __half2 h; unsigned int u; };

__device__ __forceinline__ float bf2f(u16 u) {
  union { unsigned int i; float f; } v; v.i = ((unsigned int)u) << 16; return v.f;
}
__device__ __forceinline__ u16 f2bf(float f) {
  union { float f; unsigned int i; } v; v.f = f;
  return (u16)((v.i + 0x7fffu + ((v.i >> 16) & 1u)) >> 16);  // RNE
}
// tanh-form GELU via sigmoid: x*sigmoid(1.59577(x+0.044715x^3)); |dev from erf-GELU| <= ~5e-4
__device__ __forceinline__ float gelu_f(float x) {
  float u = x * (1.5957691216057308f + 0.071354816272f * x * x);
  return x / (1.0f + __expf(-u));
}

// async global->LDS, 16B per lane. LDS dest must be wave-uniform base + lane*16.
__device__ __forceinline__ void async16(const u16* g, u16* l) {
  __builtin_amdgcn_global_load_lds(
      (const __attribute__((address_space(1))) unsigned int*)g,
      (__attribute__((address_space(3))) unsigned int*)l, 16, 0, 0);
}

// Zero the 1-px border of a [B][258][258][128] bf16 buffer. idx < 2*4*258*128.
__global__ __launch_bounds__(256) void border_zero(u16* __restrict__ buf) {
  int idx = blockIdx.x * 256 + threadIdx.x;
  int c = idx & 127;
  int t = idx >> 7;
  int pos = t % 258;
  int side = (t / 258) & 3;
  int b = t / (258 * 4);
  int h, w;
  if (side == 0) { h = 0;   w = pos; }
  else if (side == 1) { h = 257; w = pos; }
  else if (side == 2) { h = pos; w = 0; }
  else { h = pos; w = 257; }
  buf[(((size_t)b * HP_ + h) * WP_ + w) * C_ + c] = 0;
}

// NCHW fp32 -> NHWC bf16 (optionally into padded interior). 64ch x 64px tiles via LDS.
__global__ __launch_bounds__(256) void to_nhwc(const float* __restrict__ in, u16* __restrict__ out,
                                               int OHp, int OWp, int opad) {
  __shared__ u16 l[64 * 66];
  int tid = threadIdx.x;
  int b = blockIdx.z >> 1, c0 = (blockIdx.z & 1) * 64;
  int h = blockIdx.y, w0 = blockIdx.x * 64;
  for (int it = 0; it < 16; ++it) {
    int lin = it * 256 + tid;
    int c = lin >> 6, w = lin & 63;
    l[c * 66 + w] = f2bf(in[(((size_t)b * C_ + c0 + c) * H_ + h) * W_ + w0 + w]);
  }
  __syncthreads();
  for (int it = 0; it < 16; ++it) {
    int lin = it * 256 + tid;
    int w = lin >> 6, c = lin & 63;
    out[(((size_t)b * OHp + h + opad) * OWp + (w0 + w + opad)) * C_ + c0 + c] = l[c * 66 + w];
  }
}

// Repack conv weights, bf16, concatenated into wbuf:
// W1c @0      : combined ow1+ww1 fragment-packed [tap][cq][g 10][kb][lr][e] = 184320
//               (g*16+lr = co; co<128 -> ow1, co>=128 -> ww1[co-128])
// W2  @184320 : ow2 fragment-packed GT=1, co 8->16 zero-pad = 18432
// fw1 @202752 : row-major [co][ci] 16384
// fw2 @219136 : row-major [co][ci] 16384     total 235520
__global__ __launch_bounds__(256) void repack_weights(
    const float* __restrict__ ow1, const float* __restrict__ ow2,
    const float* __restrict__ ww1, const float* __restrict__ fw1,
    const float* __restrict__ fw2, u16* __restrict__ wb) {
  int idx = blockIdx.x * 256 + threadIdx.x;
  float v;
  if (idx < 184320) {
    int e = idx & 7, lr = (idx >> 3) & 15, kb = (idx >> 7) & 3;
    int t = idx >> 9;            // g + 10*(cq + 4*tap)
    int g = t % 10, u = t / 10;
    int cq = u & 3, tap = u >> 2;
    int ci = cq * 32 + kb * 8 + e, co = g * 16 + lr;
    v = (co < 128) ? ow1[(co * 128 + ci) * 9 + tap]
                   : ww1[((co - 128) * 128 + ci) * 9 + tap];
  } else if (idx < 202752) {
    int j = idx - 184320;
    int e = j & 7, lr = (j >> 3) & 15, kb = (j >> 7) & 3;
    int cq = (j >> 9) & 3, tap = j >> 11;
    int ci = cq * 32 + kb * 8 + e, co = lr;
    v = (co < 8) ? ow2[(co * 128 + ci) * 9 + tap] : 0.0f;
  } else if (idx < 219136) {
    v = fw1[idx - 202752];
  } else {
    v = fw2[idx - 219136];
  }
  wb[idx] = f2bf(v);
}

// 3x3 implicit-GEMM conv, 3-row LDS staging (A staged once per ci-quarter; 9 taps consume),
// B fragments direct from global (fragment-packed, L2-hot). Fixed geometry: Hp=Wp=258 padded
// input, W=256 output, BM=128 (2 w-tiles), grid = 1024 blocks, XCD-swizzled decode:
//   xcd=id&7 owns h-band [32*xcd, 32*xcd+32) -> rows L2-resident per XCD.
// EPI 1: +bias1 fp32 -> outf [b][p][8], co<8
// EPI 3: combined: co<128 GELU->outb (padded NHWC, OC=128); co>=128 GELU->outw [b][p][32]
template <int BM, int BN, int WR, int WC, int GT, int EPI>
__global__ __launch_bounds__(256) void gemm_conv3(
    const u16* __restrict__ A, const u16* __restrict__ Wf,
    const float* __restrict__ bias1, const float* __restrict__ bias2,
    u16* __restrict__ outb, u16* __restrict__ outw, float* __restrict__ outf) {
  constexpr int TM = BM / WR / 16, TN = BN / WC / 16;
  constexpr int RP = BM + 16;       // row pitch in px; RP*4 chunks/row (mult of 64)
  constexpr int CHR = RP * 4;
  __shared__ __align__(16) u16 As[3 * RP * 32];
  const int tid = threadIdx.x, lane = tid & 63, wave = tid >> 6;
  const int id = blockIdx.x;
  const int s = id >> 3;
  const int h = ((id & 7) << 5) | (s & 31);
  const int w0 = ((s >> 5) & 1) * BM;
  const int b = (s >> 6) & 1;
  const int wm = (wave / WC) * (BM / WR), wn = (wave % WC) * (BN / WC);
  const int lr = lane & 15, kq = lane >> 4;
  const int gbase = wn >> 4;

  int preA[TM][3];
#pragma unroll
  for (int i = 0; i < TM; i++)
#pragma unroll
    for (int kx = 0; kx < 3; kx++) {
      int row = wm + i * 16 + lr + kx;
      preA[i][kx] = row * 64 + (((kq ^ (row >> 1)) & 3) << 4);
    }

  f32x4 acc[TM][TN];
#pragma unroll
  for (int i = 0; i < TM; i++)
#pragma unroll
    for (int j = 0; j < TN; j++) { f32x4 z = {0.f, 0.f, 0.f, 0.f}; acc[i][j] = z; }

  const size_t rowpx = ((size_t)b * HP_ + h) * WP_ + w0;
  for (int cq = 0; cq < 4; ++cq) {
    const int ci0 = cq * 32;
    __syncthreads();
    for (int i = tid; i < 3 * CHR; i += 256) {
      int ky = i / CHR;
      int rem = i - ky * CHR;
      int px = rem >> 2, cb = rem & 3;
      async16(A + (rowpx + (size_t)ky * WP_ + px) * 128 + ci0 + (((cb ^ (px >> 1)) & 3) << 3),
              As + i * 8);
    }
    __syncthreads();
#pragma unroll
    for (int tap = 0; tap < 9; ++tap) {
      const int ky = tap / 3, kx = tap % 3;
      bf16x8 bfr[TN], af[TM];
#pragma unroll
      for (int j = 0; j < TN; ++j)
        bfr[j] = *(const bf16x8*)&Wf[(size_t)((((tap * 4 + cq) * GT + gbase + j) * 4 + kq) * 16 + lr) * 8];
#pragma unroll
      for (int i = 0; i < TM; ++i)
        af[i] = *(const bf16x8*)((const char*)As + ky * (RP * 64) + preA[i][kx]);
#pragma unroll
      for (int i = 0; i < TM; i++)
#pragma unroll
        for (int j = 0; j < TN; j++)
          acc[i][j] = __builtin_amdgcn_mfma_f32_16x16x32_bf16(af[i], bfr[j], acc[i][j], 0, 0, 0);
    }
  }

#pragma unroll
  for (int i = 0; i < TM; i++) {
#pragma unroll
    for (int j = 0; j < TN; j++) {
      const int co = wn + j * 16 + lr;
#pragma unroll
      for (int r = 0; r < 4; r++) {
        const int w = w0 + wm + i * 16 + (lane >> 4) * 4 + r;
        float v = acc[i][j][r];
        if (EPI == 3) {
          if (co < 128) {
            v = gelu_f(v + bias1[co]);
            outb[(((size_t)b * HP_ + h + 1) * WP_ + (w + 1)) * 128 + co] = f2bf(v);
          } else {
            v = gelu_f(v + bias2[co - 128]);
            outw[((size_t)b * P_ + (size_t)h * W_ + w) * 32 + (co - 128)] = f2bf(v);
          }
        } else {
          if (co < 8)
            outf[((size_t)b * P_ + (size_t)h * W_ + w) * 8 + co] = v + bias1[co];
        }
      }
    }
  }
}

// 1x1 implicit-GEMM (fusion convs), m97-style LDS staging for A and B. BK=64.
// EPI 0: GELU -> bf16 [b][p][128]; EPI 2: fp32 NCHW residual out = resid + 0.3*(acc+bias)
template <int BM, int BN, int WR, int WC, int EPI>
__global__ __launch_bounds__(256) void gemm_conv(
    const u16* __restrict__ A, const u16* __restrict__ Wt,
    const float* __restrict__ bias,
    u16* __restrict__ outb, float* __restrict__ outf,
    const float* __restrict__ resid) {
  constexpr int TM = BM / WR / 16, TN = BN / WC / 16;
  __shared__ __align__(16) u16 As[BM * 64];
  __shared__ __align__(16) u16 Bs[BN * 64];
  const int tid = threadIdx.x, lane = tid & 63, wave = tid >> 6;
  const int h = blockIdx.y, w0 = blockIdx.x * BM;
  const int b = blockIdx.z;
  const int wr = wave / WC, wc = wave % WC;
  const int wm = wr * (BM / WR), wn = wc * (BN / WC);
  const int lr = lane & 15;
  const int sw = (lr & 7);

  f32x4 acc[TM][TN];
#pragma unroll
  for (int i = 0; i < TM; i++)
#pragma unroll
    for (int j = 0; j < TN; j++) { f32x4 z = {0.f, 0.f, 0.f, 0.f}; acc[i][j] = z; }

  for (int c = 0; c < 2; ++c) {
    const int ci0 = c << 6;
    const u16* Ab = A + (((size_t)b * H_ + h) * W_ + w0) * 128 + ci0;
    const u16* Wb = Wt + ci0;
    __syncthreads();
    for (int i = tid; i < BM * 8; i += 256) {
      int r = i >> 3, cb = i & 7;
      async16(Ab + r * 128 + ((cb ^ (r & 7)) << 3), As + i * 8);
    }
    for (int i = tid; i < BN * 8; i += 256) {
      int r = i >> 3, cb = i & 7;
      async16(Wb + r * 128 + ((cb ^ (r & 7)) << 3), Bs + i * 8);
    }
    __syncthreads();
#pragma unroll
    for (int ks = 0; ks < 2; ++ks) {
      const int kb = ks * 4 + (lane >> 4);
      bf16x8 af[TM], bfr[TN];
#pragma unroll
      for (int i = 0; i < TM; i++)
        af[i] = *(const bf16x8*)&As[(wm + i * 16 + lr) * 64 + ((kb ^ sw) << 3)];
#pragma unroll
      for (int j = 0; j < TN; j++)
        bfr[j] = *(const bf16x8*)&Bs[(wn + j * 16 + lr) * 64 + ((kb ^ sw) << 3)];
#pragma unroll
      for (int i = 0; i < TM; i++)
#pragma unroll
        for (int j = 0; j < TN; j++)
          acc[i][j] = __builtin_amdgcn_mfma_f32_16x16x32_bf16(af[i], bfr[j], acc[i][j], 0, 0, 0);
    }
  }

#pragma unroll
  for (int i = 0; i < TM; i++) {
#pragma unroll
    for (int j = 0; j < TN; j++) {
      const int co = wn + j * 16 + lr;
      if (EPI == 2) {
        const int w = w0 + wm + i * 16 + (lane >> 4) * 4;
        size_t idx = ((size_t)b * 128 + co) * (size_t)P_ + (size_t)h * W_ + w;
        float4 rv = *(const float4*)&resid[idx];
        float bi = bias[co];
        float4 ov;
        ov.x = rv.x + 0.3f * (acc[i][j][0] + bi);
        ov.y = rv.y + 0.3f * (acc[i][j][1] + bi);
        ov.z = rv.z + 0.3f * (acc[i][j][2] + bi);
        ov.w = rv.w + 0.3f * (acc[i][j][3] + bi);
        *(float4*)&outf[idx] = ov;
      } else {
#pragma unroll
        for (int r = 0; r < 4; r++) {
          const int w = w0 + wm + i * 16 + (lane >> 4) * 4 + r;
          float v = gelu_f(acc[i][j][r] + bias[co]);
          outb[(((size_t)b * H_ + h) * W_ + w) * 128 + co] = f2bf(v);
        }
      }
    }
  }
}

// Per-pixel prep (lane-parallel): logits = 1x1 conv 32->4, softmax, grid math.
// Emits per (pix,k) descriptor: {base|dx<<16|dy<<17, half2(w00,w01), half2(w10,w11), 0}.
__global__ __launch_bounds__(256) void prep(
    const float* __restrict__ offs, const u16* __restrict__ w1,
    const float* __restrict__ ww2, const float* __restrict__ wb2,
    uint4* __restrict__ desc) {
  const int pix = blockIdx.x * 256 + threadIdx.x;
  const int p = pix & 65535, h = p >> 8, w = p & 255;
  const u16* wp = w1 + (size_t)pix * 32;
  float f[32];
#pragma unroll
  for (int i = 0; i < 32; i += 2) {
    unsigned int u = *(const unsigned int*)&wp[i];
    f[i] = bf2f((u16)u); f[i + 1] = bf2f((u16)(u >> 16));
  }
  float lg[4];
#pragma unroll
  for (int k = 0; k < 4; k++) {
    float s = wb2[k];
#pragma unroll
    for (int i = 0; i < 32; i++) s = fmaf(ww2[k * 32 + i], f[i], s);
    lg[k] = s;
  }
  float mx = fmaxf(fmaxf(lg[0], lg[1]), fmaxf(lg[2], lg[3]));
  float e[4], sum = 0.f;
#pragma unroll
  for (int k = 0; k < 4; k++) { e[k] = __expf(lg[k] - mx); sum += e[k]; }
  const float inv = 1.0f / sum;

  const float* op = offs + (size_t)pix * 8;
#pragma unroll
  for (int k = 0; k < 4; k++) {
    float gx = (2.0f * w / 255.0f - 1.0f) + op[2 * k] * (1.0f / 128.0f);
    float gy = (2.0f * h / 255.0f - 1.0f) + op[2 * k + 1] * (1.0f / 128.0f);
    gx = fminf(fmaxf(gx, -1.f), 1.f);
    gy = fminf(fmaxf(gy, -1.f), 1.f);
    float px = fminf(fmaxf((gx + 1.f) * 127.5f, 0.f), 255.f);
    float py = fminf(fmaxf((gy + 1.f) * 127.5f, 0.f), 255.f);
    int x0 = (int)px, y0 = (int)py;          // >= 0: trunc == floor
    int x1 = min(x0 + 1, 255), y1 = min(y0 + 1, 255);
    float wx = px - x0, wy = py - y0;
    float wk = e[k] * inv;
    float w00 = (1.f - wx) * (1.f - wy) * wk, w01 = wx * (1.f - wy) * wk;
    float w10 = (1.f - wx) * wy * wk,         w11 = wx * wy * wk;
    HU t01, t23;
    t01.h = __floats2half2_rn(w00, w01);
    t23.h = __floats2half2_rn(w10, w11);
    uint4 d;
    d.x = (unsigned)(y0 * 256 + x0) | ((unsigned)(x1 - x0) << 16) | ((unsigned)(y1 - y0) << 17);
    d.y = t01.u; d.z = t23.u; d.w = 0;
    desc[(size_t)pix * 4 + k] = d;
  }
}

// Lean sampler: wave per pixel, lane = channel pair. 16 gathers + 16 FMA per lane.
__global__ __launch_bounds__(256) void sampler(
    const uint4* __restrict__ desc, const u16* __restrict__ keyn, u16* __restrict__ agg) {
  const int tid = threadIdx.x, lane = tid & 63, wv = tid >> 6;
  const int pix = blockIdx.x * 4 + wv;
  const int b = pix >> 16;
  const u16* kb = keyn + (size_t)b * (P_ * C_) + 2 * lane;
  float a0 = 0.f, a1 = 0.f;
#pragma unroll
  for (int k = 0; k < 4; ++k) {
    uint4 d = desc[(size_t)pix * 4 + k];
    const int boff = (int)(d.x & 0xFFFFu) << 7;
    const int o01 = (int)((d.x >> 16) & 1u) << 7;
    const int o10 = (int)((d.x >> 17) & 1u) << 15;
    const u16* c0 = kb + boff;
    unsigned u00 = *(const unsigned*)(c0);
    unsigned u01 = *(const unsigned*)(c0 + o01);
    unsigned u10 = *(const unsigned*)(c0 + o10);
    unsigned u11 = *(const unsigned*)(c0 + o10 + o01);
    HU t01, t23; t01.u = d.y; t23.u = d.z;
    float2 wA = __half22float2(t01.h);
    float2 wB = __half22float2(t23.h);
    a0 = fmaf(wA.x, bf2f((u16)u00), a0);
    a0 = fmaf(wA.y, bf2f((u16)u01), a0);
    a0 = fmaf(wB.x, bf2f((u16)u10), a0);
    a0 = fmaf(wB.y, bf2f((u16)u11), a0);
    a1 = fmaf(wA.x, bf2f((u16)(u00 >> 16)), a1);
    a1 = fmaf(wA.y, bf2f((u16)(u01 >> 16)), a1);
    a1 = fmaf(wB.x, bf2f((u16)(u10 >> 16)), a1);
    a1 = fmaf(wB.y, bf2f((u16)(u11 >> 16)), a1);
  }
  unsigned outu = ((unsigned)f2bf(a1) << 16) | (unsigned)f2bf(a0);
  *(unsigned*)&agg[(size_t)pix * C_ + 2 * lane] = outu;
}

extern "C" void kernel_launch(void* const* d_in, const int* in_sizes, int n_in,
                              void* d_out, int out_size, void* d_ws, size_t ws_size,
                              hipStream_t stream) {
  (void)in_sizes; (void)n_in; (void)out_size; (void)ws_size;
  const float* q   = (const float*)d_in[0];
  const float* key = (const float*)d_in[1];
  const float* ow1 = (const float*)d_in[2];
  const float* ob1 = (const float*)d_in[3];
  const float* ow2 = (const float*)d_in[4];
  const float* ob2 = (const float*)d_in[5];
  const float* ww1 = (const float*)d_in[6];
  const float* wb1 = (const float*)d_in[7];
  const float* ww2 = (const float*)d_in[8];
  const float* wb2 = (const float*)d_in[9];
  const float* fw1 = (const float*)d_in[10];
  const float* fb1 = (const float*)d_in[11];
  const float* fw2 = (const float*)d_in[12];
  const float* fb2 = (const float*)d_in[13];
  float* out = (float*)d_out;
  char* ws = (char*)d_ws;

  // workspace layout (bytes): total ~114.8 MB
  u16* qpad   = (u16*)(ws);                  // [2][258][258][128] bf16, 34,080,768 B
  u16* t1pad  = (u16*)(ws + 34080768);       // same shape (reused as agg)
  u16* keyn   = (u16*)(ws + 68161536);       // [2][65536][128] bf16, 33,554,432 B
  float* offs = (float*)(ws + 101715968);    // [2][65536][8] fp32,    4,194,304 B
  u16* w1b    = (u16*)(ws + 105910272);      // [2][65536][32] bf16,   8,388,608 B
  u16* wbuf   = (u16*)(ws + 114298880);      // 235520 bf16 weights,     471,040 B
  u16* t2  = qpad;                           // fusion temp [2][65536][128] bf16 (16.8 MB)
  u16* agg = t1pad;
  uint4* desc = (uint4*)(ws + 16777216);     // [2*65536][4] x 16B = 8,388,608 B (qpad dead)

  border_zero<<<1032, 256, 0, stream>>>(qpad);
  border_zero<<<1032, 256, 0, stream>>>(t1pad);
  repack_weights<<<920, 256, 0, stream>>>(ow1, ow2, ww1, fw1, fw2, wbuf);
  to_nhwc<<<dim3(4, 256, 4), 256, 0, stream>>>(q, qpad, HP_, WP_, 1);
  to_nhwc<<<dim3(4, 256, 4), 256, 0, stream>>>(key, keyn, H_, W_, 0);

  // combined ow1 (3x3 128->128 +GELU -> t1pad) + ww1 (3x3 128->32 +GELU -> w1b)
  gemm_conv3<128, 160, 2, 2, 10, 3><<<1024, 256, 0, stream>>>(
      qpad, wbuf, ob1, wb1, t1pad, w1b, nullptr);
  // offset_net conv2 (3x3 128->8) -> offs fp32
  gemm_conv3<128, 16, 4, 1, 1, 1><<<1024, 256, 0, stream>>>(
      t1pad, wbuf + 184320, ob2, nullptr, nullptr, nullptr, offs);
  // logits + softmax + grid math -> descriptors
  prep<<<512, 256, 0, stream>>>(offs, w1b, ww2, wb2, desc);
  // gather + weighted sum -> agg
  sampler<<<32768, 256, 0, stream>>>(desc, keyn, agg);
  // fusion conv1 (1x1) + GELU -> t2
  gemm_conv<128, 128, 2, 2, 0><<<dim3(2, 256, 2), 256, 0, stream>>>(
      agg, wbuf + 202752, fb1, t2, nullptr, nullptr);
  // fusion conv2 (1x1) + residual -> out (NCHW fp32)
  gemm_conv<128, 128, 2, 2, 2><<<dim3(2, 256, 2), 256, 0, stream>>>(
      t2, wbuf + 219136, fb2, nullptr, out, q);
}

// Round 5
// 357.552 us; speedup vs baseline: 1.4427x; 1.1118x over previous
//
#include <hip/hip_runtime.h>
#include <hip/hip_fp16.h>

typedef unsigned short u16;
typedef __attribute__((ext_vector_type(8))) short bf16x8;
typedef __attribute__((ext_vector_type(4))) float f32x4;

constexpr int B_ = 2, C_ = 128, H_ = 256, W_ = 256, P_ = H_ * W_;
constexpr int HP_ = 258, WP_ = 258;

union HU { __half2 h; unsigned int u; };

__device__ __forceinline__ float bf2f(u16 u) {
  union { unsigned int i; float f; } v; v.i = ((unsigned int)u) << 16; return v.f;
}
__device__ __forceinline__ u16 f2bf(float f) {
  union { float f; unsigned int i; } v; v.f = f;
  return (u16)((v.i + 0x7fffu + ((v.i >> 16) & 1u)) >> 16);  // RNE
}
// tanh-form GELU via sigmoid; |dev from erf-GELU| <= ~5e-4
__device__ __forceinline__ float gelu_f(float x) {
  float u = x * (1.5957691216057308f + 0.071354816272f * x * x);
  return x / (1.0f + __expf(-u));
}

// async global->LDS, 16B per lane. LDS dest must be wave-uniform base + lane*16.
__device__ __forceinline__ void async16(const u16* g, u16* l) {
  __builtin_amdgcn_global_load_lds(
      (const __attribute__((address_space(1))) unsigned int*)g,
      (__attribute__((address_space(3))) unsigned int*)l, 16, 0, 0);
}

// ---------------- prologue: to_nhwc(q), to_nhwc(key), border-zero x2, repack ----------
// grid: [0,8192) nhwc transposes; [8192,10256) border; [10256,11176) repack
__global__ __launch_bounds__(256) void prologue(
    const float* __restrict__ q, const float* __restrict__ key,
    const float* __restrict__ ow1, const float* __restrict__ ow2,
    const float* __restrict__ ww1, const float* __restrict__ fw1,
    const float* __restrict__ fw2,
    u16* __restrict__ qpad, u16* __restrict__ keyn, u16* __restrict__ t1pad,
    u16* __restrict__ wb) {
  __shared__ u16 l[64 * 66];
  const int id = blockIdx.x, tid = threadIdx.x;
  if (id < 8192) {
    int z = id >> 10, r = id & 1023;
    int bx = r & 3, by = r >> 2;
    const float* in; u16* out; int OW, opad;
    if (z < 4) { in = q; out = qpad; OW = WP_; opad = 1; }
    else { z -= 4; in = key; out = keyn; OW = W_; opad = 0; }
    int b = z >> 1, c0 = (z & 1) * 64;
    int h = by, w0 = bx * 64;
    for (int it = 0; it < 16; ++it) {
      int lin = it * 256 + tid;
      int c = lin >> 6, w = lin & 63;
      l[c * 66 + w] = f2bf(in[(((size_t)b * C_ + c0 + c) * H_ + h) * W_ + w0 + w]);
    }
    __syncthreads();
    int OH = (opad ? HP_ : H_);
    for (int it = 0; it < 16; ++it) {
      int lin = it * 256 + tid;
      int w = lin >> 6, c = lin & 63;
      out[(((size_t)b * OH + h + opad) * OW + (w0 + w + opad)) * C_ + c0 + c] = l[c * 66 + w];
    }
  } else if (id < 10256) {
    int j = id - 8192;
    u16* buf = (j < 1032) ? qpad : t1pad;
    int idx = ((j < 1032) ? j : j - 1032) * 256 + tid;
    int c = idx & 127;
    int t = idx >> 7;
    int pos = t % 258;
    int side = (t / 258) & 3;
    int b = t / (258 * 4);
    int h, w;
    if (side == 0) { h = 0; w = pos; }
    else if (side == 1) { h = 257; w = pos; }
    else if (side == 2) { h = pos; w = 0; }
    else { h = pos; w = 257; }
    buf[(((size_t)b * HP_ + h) * WP_ + w) * C_ + c] = 0;
  } else {
    // repack weights into wbuf (bf16):
    // W1c @0: ow1+ww1 fragment-packed [tap][cq][g 10][kb 4][lr 16][e 8] = 184320
    // W2 @184320: ow2 packed GT=1, co 8->16 zero-pad = 18432
    // fw1 @202752 row-major [co][ci] 16384 ; fw2 @219136 row-major 16384
    int idx = (id - 10256) * 256 + tid;
    float v;
    if (idx < 184320) {
      int e = idx & 7, lr = (idx >> 3) & 15, kb = (idx >> 7) & 3;
      int t = idx >> 9;
      int g = t % 10, u = t / 10;
      int cq = u & 3, tap = u >> 2;
      int ci = cq * 32 + kb * 8 + e, co = g * 16 + lr;
      v = (co < 128) ? ow1[(co * 128 + ci) * 9 + tap]
                     : ww1[((co - 128) * 128 + ci) * 9 + tap];
    } else if (idx < 202752) {
      int j = idx - 184320;
      int e = j & 7, lr = (j >> 3) & 15, kb = (j >> 7) & 3;
      int cq = (j >> 9) & 3, tap = j >> 11;
      int ci = cq * 32 + kb * 8 + e, co = lr;
      v = (co < 8) ? ow2[(co * 128 + ci) * 9 + tap] : 0.0f;
    } else if (idx < 219136) {
      v = fw1[idx - 202752];
    } else {
      v = fw2[idx - 219136];
    }
    wb[idx] = f2bf(v);
  }
}

// ---------------- combined 3x3 conv (ow1 128->128 + ww1 128->32), band-tiled ----------
// BM=128 as 4 rows x 32 px; BN=160 (GT=10); staging 6 rows x 36 px per ci-quarter.
// XCD swizzle: id&7 owns h-bands [32*(id&7), +32).
__global__ __launch_bounds__(256) void conv3_big(
    const u16* __restrict__ A, const u16* __restrict__ Wf,
    const float* __restrict__ bias1, const float* __restrict__ bias2,
    u16* __restrict__ outb, u16* __restrict__ outw) {
  constexpr int RPX = 36, ROWU = RPX * 32;          // u16 per row-plane = 1152
  __shared__ __align__(16) u16 As[6 * ROWU];        // 13,824 B
  const int tid = threadIdx.x, lane = tid & 63, wave = tid >> 6;
  const int id = blockIdx.x;
  const int s = id >> 3;
  const int h0 = (((id & 7) << 3) | (s & 7)) << 2;  // 4-row band
  const int w0 = ((s >> 3) & 7) << 5;
  const int b = s >> 6;
  const int wr = wave >> 1, wc = wave & 1;
  const int wm = wr * 64, wn = wc * 80;
  const int lr = lane & 15, kq = lane >> 4;
  const int gbase = wn >> 4;

  int rbase[4], pxb[4], preA[4][3];
#pragma unroll
  for (int i = 0; i < 4; i++) {
    rbase[i] = (wm + i * 16) >> 5;
    pxb[i] = (wm + i * 16) & 31;
#pragma unroll
    for (int kx = 0; kx < 3; kx++) {
      int pxv = pxb[i] + lr + kx;
      preA[i][kx] = (pxv * 4 + (kq ^ ((pxv >> 1) & 3))) * 8;  // u16 units
    }
  }

  f32x4 acc[4][5];
#pragma unroll
  for (int i = 0; i < 4; i++)
#pragma unroll
    for (int j = 0; j < 5; j++) { f32x4 z = {0.f, 0.f, 0.f, 0.f}; acc[i][j] = z; }

  for (int cq = 0; cq < 4; ++cq) {
    const int ci0 = cq * 32;
    __syncthreads();
    for (int i = tid; i < 864; i += 256) {
      int ry = i / 144;
      int rem = i - ry * 144;
      int px = rem >> 2, c8 = rem & 3;
      int g = c8 ^ ((px >> 1) & 3);
      async16(A + ((size_t)(b * HP_ + h0 + ry) * WP_ + (w0 + px)) * 128 + ci0 + g * 8,
              As + i * 8);
    }
    __syncthreads();
#pragma unroll
    for (int tap = 0; tap < 9; ++tap) {
      const int ky = tap / 3, kx = tap % 3;
      bf16x8 bfr[5], af[4];
#pragma unroll
      for (int j = 0; j < 5; ++j)
        bfr[j] = *(const bf16x8*)&Wf[(size_t)((((tap * 4 + cq) * 10 + gbase + j) * 4 + kq) * 16 + lr) * 8];
#pragma unroll
      for (int i = 0; i < 4; ++i)
        af[i] = *(const bf16x8*)&As[(rbase[i] + ky) * ROWU + preA[i][kx]];
#pragma unroll
      for (int i = 0; i < 4; i++)
#pragma unroll
        for (int j = 0; j < 5; j++)
          acc[i][j] = __builtin_amdgcn_mfma_f32_16x16x32_bf16(af[i], bfr[j], acc[i][j], 0, 0, 0);
    }
  }

#pragma unroll
  for (int i = 0; i < 4; i++) {
    const int h = h0 + rbase[i];
#pragma unroll
    for (int j = 0; j < 5; j++) {
      const int co = wn + j * 16 + lr;
#pragma unroll
      for (int r = 0; r < 4; r++) {
        const int w = w0 + pxb[i] + (lane >> 4) * 4 + r;
        float v = acc[i][j][r];
        if (co < 128) {
          v = gelu_f(v + bias1[co]);
          outb[(((size_t)b * HP_ + h + 1) * WP_ + (w + 1)) * 128 + co] = f2bf(v);
        } else {
          v = gelu_f(v + bias2[co - 128]);
          outw[((size_t)b * P_ + (size_t)h * W_ + w) * 32 + (co - 128)] = f2bf(v);
        }
      }
    }
  }
}

// ---------------- offsets conv (3x3 128->8) + fused prep epilogue ---------------------
// BM=256 as 4 rows x 64 px; BN=16; wave = one row. Epilogue: offs->LDS regroup,
// then per-thread pixel: logits(32->4), softmax, grid math -> desc.
__global__ __launch_bounds__(256) void conv_off(
    const u16* __restrict__ A, const u16* __restrict__ Wf,
    const float* __restrict__ bias,
    const u16* __restrict__ w1b, const float* __restrict__ ww2,
    const float* __restrict__ wb2, uint4* __restrict__ desc) {
  constexpr int RPX = 66, ROWU = RPX * 32;          // 2112 u16 per row-plane
  __shared__ __align__(16) u16 As[6 * ROWU];        // 25,344 B
  float* off_lds = (float*)As;                      // reused after K-loop (256*9*4 B)
  const int tid = threadIdx.x, lane = tid & 63, wave = tid >> 6;
  const int id = blockIdx.x;
  const int s = id >> 3;
  const int h0 = (((id & 7) << 3) | (s & 7)) << 2;
  const int w0 = ((s >> 3) & 3) << 6;
  const int b = s >> 5;
  const int lr = lane & 15, kq = lane >> 4;

  int preA[4][3];
#pragma unroll
  for (int i = 0; i < 4; i++)
#pragma unroll
    for (int kx = 0; kx < 3; kx++) {
      int pxv = i * 16 + lr + kx;
      preA[i][kx] = (pxv * 4 + (kq ^ ((pxv >> 1) & 3))) * 8;
    }

  f32x4 acc[4];
#pragma unroll
  for (int i = 0; i < 4; i++) { f32x4 z = {0.f, 0.f, 0.f, 0.f}; acc[i] = z; }

  for (int cq = 0; cq < 4; ++cq) {
    const int ci0 = cq * 32;
    __syncthreads();
    for (int i = tid; i < 1584; i += 256) {
      int ry = i / 264;
      int rem = i - ry * 264;
      int px = rem >> 2, c8 = rem & 3;
      int g = c8 ^ ((px >> 1) & 3);
      async16(A + ((size_t)(b * HP_ + h0 + ry) * WP_ + (w0 + px)) * 128 + ci0 + g * 8,
              As + i * 8);
    }
    __syncthreads();
#pragma unroll
    for (int tap = 0; tap < 9; ++tap) {
      const int ky = tap / 3, kx = tap % 3;
      bf16x8 bw = *(const bf16x8*)&Wf[(size_t)(((tap * 4 + cq) * 4 + kq) * 16 + lr) * 8];
      bf16x8 af[4];
#pragma unroll
      for (int i = 0; i < 4; ++i)
        af[i] = *(const bf16x8*)&As[(wave + ky) * ROWU + preA[i][kx]];
#pragma unroll
      for (int i = 0; i < 4; i++)
        acc[i] = __builtin_amdgcn_mfma_f32_16x16x32_bf16(af[i], bw, acc[i], 0, 0, 0);
    }
  }

  __syncthreads();  // staging region dead; reuse as off_lds
#pragma unroll
  for (int i = 0; i < 4; i++) {
#pragma unroll
    for (int r = 0; r < 4; r++) {
      if (lr < 8) {
        int px = i * 16 + (lane >> 4) * 4 + r;
        off_lds[(wave * 64 + px) * 9 + lr] = acc[i][r] + bias[lr];
      }
    }
  }
  __syncthreads();

  // one pixel per thread
  const int pp = tid;
  const int h = h0 + (pp >> 6), w = w0 + (pp & 63);
  const int pix = b * P_ + h * W_ + w;
  const u16* wp = w1b + (size_t)pix * 32;
  float f[32];
#pragma unroll
  for (int i = 0; i < 32; i += 2) {
    unsigned u = *(const unsigned*)&wp[i];
    f[i] = bf2f((u16)u); f[i + 1] = bf2f((u16)(u >> 16));
  }
  float lg[4];
#pragma unroll
  for (int k = 0; k < 4; k++) {
    float sacc = wb2[k];
#pragma unroll
    for (int i = 0; i < 32; i++) sacc = fmaf(ww2[k * 32 + i], f[i], sacc);
    lg[k] = sacc;
  }
  float mx = fmaxf(fmaxf(lg[0], lg[1]), fmaxf(lg[2], lg[3]));
  float e[4], sum = 0.f;
#pragma unroll
  for (int k = 0; k < 4; k++) { e[k] = __expf(lg[k] - mx); sum += e[k]; }
  const float inv = 1.0f / sum;
#pragma unroll
  for (int k = 0; k < 4; k++) {
    float ox = off_lds[pp * 9 + 2 * k], oy = off_lds[pp * 9 + 2 * k + 1];
    float gx = (2.0f * w / 255.0f - 1.0f) + ox * (1.0f / 128.0f);
    float gy = (2.0f * h / 255.0f - 1.0f) + oy * (1.0f / 128.0f);
    gx = fminf(fmaxf(gx, -1.f), 1.f);
    gy = fminf(fmaxf(gy, -1.f), 1.f);
    float px = fminf(fmaxf((gx + 1.f) * 127.5f, 0.f), 255.f);
    float py = fminf(fmaxf((gy + 1.f) * 127.5f, 0.f), 255.f);
    int x0 = (int)px, y0 = (int)py;
    int x1 = min(x0 + 1, 255), y1 = min(y0 + 1, 255);
    float wx = px - x0, wy = py - y0;
    float wk = e[k] * inv;
    float w00 = (1.f - wx) * (1.f - wy) * wk, w01 = wx * (1.f - wy) * wk;
    float w10 = (1.f - wx) * wy * wk,         w11 = wx * wy * wk;
    HU t01, t23;
    t01.h = __floats2half2_rn(w00, w01);
    t23.h = __floats2half2_rn(w10, w11);
    uint4 d;
    d.x = (unsigned)(y0 * 256 + x0) | ((unsigned)(x1 - x0) << 16) | ((unsigned)(y1 - y0) << 17);
    d.y = t01.u; d.z = t23.u; d.w = 0;
    desc[(size_t)pix * 4 + k] = d;
  }
}

// ---------------- sampler: wave per pixel, lane = channel pair ------------------------
__global__ __launch_bounds__(256) void sampler(
    const uint4* __restrict__ desc, const u16* __restrict__ keyn, u16* __restrict__ agg) {
  const int tid = threadIdx.x, lane = tid & 63, wv = tid >> 6;
  const int pix = blockIdx.x * 4 + wv;
  const int b = pix >> 16;
  const u16* kb = keyn + (size_t)b * (P_ * C_) + 2 * lane;
  float a0 = 0.f, a1 = 0.f;
#pragma unroll
  for (int k = 0; k < 4; ++k) {
    uint4 d = desc[(size_t)pix * 4 + k];
    const int boff = (int)(d.x & 0xFFFFu) << 7;
    const int o01 = (int)((d.x >> 16) & 1u) << 7;
    const int o10 = (int)((d.x >> 17) & 1u) << 15;
    const u16* c0 = kb + boff;
    unsigned u00 = *(const unsigned*)(c0);
    unsigned u01 = *(const unsigned*)(c0 + o01);
    unsigned u10 = *(const unsigned*)(c0 + o10);
    unsigned u11 = *(const unsigned*)(c0 + o10 + o01);
    HU t01, t23; t01.u = d.y; t23.u = d.z;
    float2 wA = __half22float2(t01.h);
    float2 wB = __half22float2(t23.h);
    a0 = fmaf(wA.x, bf2f((u16)u00), a0);
    a0 = fmaf(wA.y, bf2f((u16)u01), a0);
    a0 = fmaf(wB.x, bf2f((u16)u10), a0);
    a0 = fmaf(wB.y, bf2f((u16)u11), a0);
    a1 = fmaf(wA.x, bf2f((u16)(u00 >> 16)), a1);
    a1 = fmaf(wA.y, bf2f((u16)(u01 >> 16)), a1);
    a1 = fmaf(wB.x, bf2f((u16)(u10 >> 16)), a1);
    a1 = fmaf(wB.y, bf2f((u16)(u11 >> 16)), a1);
  }
  unsigned outu = ((unsigned)f2bf(a1) << 16) | (unsigned)f2bf(a0);
  *(unsigned*)&agg[(size_t)pix * C_ + 2 * lane] = outu;
}

// ---------------- fused fusion: 1x1 conv + GELU -> LDS -> 1x1 conv + residual ---------
// block = 128 px x 128 co (all of K for GEMM2 is produced in-block).
__global__ __launch_bounds__(256) void conv_fuse(
    const u16* __restrict__ Aagg, const u16* __restrict__ W1, const u16* __restrict__ W2,
    const float* __restrict__ b1, const float* __restrict__ b2,
    const float* __restrict__ resid, float* __restrict__ out) {
  __shared__ __align__(16) u16 SM[16384];   // phase1: As[0:8192) Bs[8192:16384); phase2: Bs2
  __shared__ __align__(16) u16 T2[128 * 136];  // GELU tile, px pitch 136 u16 (272B)
  u16* As = SM;
  u16* Bs = SM + 8192;
  const int tid = threadIdx.x, lane = tid & 63, wave = tid >> 6;
  const int h = blockIdx.y, w0 = blockIdx.x * 128;
  const int b = blockIdx.z;
  const int wr = wave >> 1, wc = wave & 1;
  const int wm = wr * 64, wn = wc * 64;
  const int lr = lane & 15, kq = lane >> 4;
  const int sw = lr & 7;

  f32x4 acc[4][4];
#pragma unroll
  for (int i = 0; i < 4; i++)
#pragma unroll
    for (int j = 0; j < 4; j++) { f32x4 z = {0.f, 0.f, 0.f, 0.f}; acc[i][j] = z; }

  // ---- GEMM1: agg(128px x 128ci) @ fw1 -> acc
  for (int c = 0; c < 2; ++c) {
    const int ci0 = c << 6;
    const u16* Ab = Aagg + (((size_t)b * H_ + h) * W_ + w0) * 128 + ci0;
    const u16* Wb = W1 + ci0;
    __syncthreads();
    for (int i = tid; i < 128 * 8; i += 256) {
      int r = i >> 3, cb = i & 7;
      async16(Ab + r * 128 + ((cb ^ (r & 7)) << 3), As + i * 8);
    }
    for (int i = tid; i < 128 * 8; i += 256) {
      int r = i >> 3, cb = i & 7;
      async16(Wb + r * 128 + ((cb ^ (r & 7)) << 3), Bs + i * 8);
    }
    __syncthreads();
#pragma unroll
    for (int ks = 0; ks < 2; ++ks) {
      const int kb = ks * 4 + kq;
      bf16x8 af[4], bfr[4];
#pragma unroll
      for (int i = 0; i < 4; i++)
        af[i] = *(const bf16x8*)&As[(wm + i * 16 + lr) * 64 + ((kb ^ sw) << 3)];
#pragma unroll
      for (int j = 0; j < 4; j++)
        bfr[j] = *(const bf16x8*)&Bs[(wn + j * 16 + lr) * 64 + ((kb ^ sw) << 3)];
#pragma unroll
      for (int i = 0; i < 4; i++)
#pragma unroll
        for (int j = 0; j < 4; j++)
          acc[i][j] = __builtin_amdgcn_mfma_f32_16x16x32_bf16(af[i], bfr[j], acc[i][j], 0, 0, 0);
    }
  }

  // ---- GELU -> T2 (bf16), then stage fw2 into SM
#pragma unroll
  for (int i = 0; i < 4; i++)
#pragma unroll
    for (int j = 0; j < 4; j++) {
      const int co = wn + j * 16 + lr;
#pragma unroll
      for (int r = 0; r < 4; r++) {
        const int px = wm + i * 16 + (lane >> 4) * 4 + r;
        T2[px * 136 + co] = f2bf(gelu_f(acc[i][j][r] + b1[co]));
      }
    }
  __syncthreads();
  for (int i = tid; i < 2048; i += 256) {   // 128co x 16 chunks
    int r = i >> 4, sl = i & 15;
    int g = sl ^ (r & 7);
    async16(W2 + r * 128 + g * 8, SM + i * 8);
  }
  __syncthreads();

  // ---- GEMM2: T2(128px x 128k) @ fw2 -> acc
#pragma unroll
  for (int i = 0; i < 4; i++)
#pragma unroll
    for (int j = 0; j < 4; j++) { f32x4 z = {0.f, 0.f, 0.f, 0.f}; acc[i][j] = z; }
#pragma unroll
  for (int ks = 0; ks < 4; ++ks) {
    const int kc = ks * 4 + kq;
    bf16x8 af[4], bfr[4];
#pragma unroll
    for (int i = 0; i < 4; i++)
      af[i] = *(const bf16x8*)&T2[(wm + i * 16 + lr) * 136 + kc * 8];
#pragma unroll
    for (int j = 0; j < 4; j++) {
      int rr = wn + j * 16 + lr;
      bfr[j] = *(const bf16x8*)&SM[rr * 128 + (kc ^ (rr & 7)) * 8];
    }
#pragma unroll
    for (int i = 0; i < 4; i++)
#pragma unroll
      for (int j = 0; j < 4; j++)
        acc[i][j] = __builtin_amdgcn_mfma_f32_16x16x32_bf16(af[i], bfr[j], acc[i][j], 0, 0, 0);
  }

  // ---- residual epilogue (fp32 NCHW)
#pragma unroll
  for (int i = 0; i < 4; i++) {
#pragma unroll
    for (int j = 0; j < 4; j++) {
      const int co = wn + j * 16 + lr;
      const int w = w0 + wm + i * 16 + (lane >> 4) * 4;
      size_t idx = ((size_t)b * 128 + co) * (size_t)P_ + (size_t)h * W_ + w;
      float4 rv = *(const float4*)&resid[idx];
      float bi = b2[co];
      float4 ov;
      ov.x = rv.x + 0.3f * (acc[i][j][0] + bi);
      ov.y = rv.y + 0.3f * (acc[i][j][1] + bi);
      ov.z = rv.z + 0.3f * (acc[i][j][2] + bi);
      ov.w = rv.w + 0.3f * (acc[i][j][3] + bi);
      *(float4*)&out[idx] = ov;
    }
  }
}

extern "C" void kernel_launch(void* const* d_in, const int* in_sizes, int n_in,
                              void* d_out, int out_size, void* d_ws, size_t ws_size,
                              hipStream_t stream) {
  (void)in_sizes; (void)n_in; (void)out_size; (void)ws_size;
  const float* q   = (const float*)d_in[0];
  const float* key = (const float*)d_in[1];
  const float* ow1 = (const float*)d_in[2];
  const float* ob1 = (const float*)d_in[3];
  const float* ow2 = (const float*)d_in[4];
  const float* ob2 = (const float*)d_in[5];
  const float* ww1 = (const float*)d_in[6];
  const float* wb1 = (const float*)d_in[7];
  const float* ww2 = (const float*)d_in[8];
  const float* wb2 = (const float*)d_in[9];
  const float* fw1 = (const float*)d_in[10];
  const float* fb1 = (const float*)d_in[11];
  const float* fw2 = (const float*)d_in[12];
  const float* fb2 = (const float*)d_in[13];
  float* out = (float*)d_out;
  char* ws = (char*)d_ws;

  // workspace: qpad @0 (34.08MB, reused as desc after conv3_big); t1pad @34080768
  // (34.08MB, reused as agg); keyn @68161536 (33.55MB); w1b @101715968 (8.39MB);
  // wbuf @110104576 (471KB). peak 110.6MB.
  u16* qpad  = (u16*)(ws);
  u16* t1pad = (u16*)(ws + 34080768);
  u16* keyn  = (u16*)(ws + 68161536);
  u16* w1b   = (u16*)(ws + 101715968);
  u16* wbuf  = (u16*)(ws + 110104576);
  uint4* desc = (uint4*)ws;        // qpad dead after conv3_big
  u16* agg = t1pad;                // t1pad dead after conv_off

  prologue<<<11176, 256, 0, stream>>>(q, key, ow1, ow2, ww1, fw1, fw2,
                                      qpad, keyn, t1pad, wbuf);
  conv3_big<<<1024, 256, 0, stream>>>(qpad, wbuf, ob1, wb1, t1pad, w1b);
  conv_off<<<512, 256, 0, stream>>>(t1pad, wbuf + 184320, ob2, w1b, ww2, wb2, desc);
  sampler<<<32768, 256, 0, stream>>>(desc, keyn, agg);
  conv_fuse<<<dim3(2, 256, 2), 256, 0, stream>>>(agg, wbuf + 202752, wbuf + 219136,
                                                 fb1, fb2, q, out);
}

// Round 6
// 355.303 us; speedup vs baseline: 1.4518x; 1.0063x over previous
//
#include <hip/hip_runtime.h>
#include <hip/hip_fp16.h>

typedef unsigned short u16;
typedef __attribute__((ext_vector_type(8))) short bf16x8;
typedef __attribute__((ext_vector_type(4))) float f32x4;

constexpr int B_ = 2, C_ = 128, H_ = 256, W_ = 256, P_ = H_ * W_;
constexpr int HP_ = 258, WP_ = 258;

union HU { __half2 h; unsigned int u; };

__device__ __forceinline__ float bf2f(u16 u) {
  union { unsigned int i; float f; } v; v.i = ((unsigned int)u) << 16; return v.f;
}
__device__ __forceinline__ u16 f2bf(float f) {
  union { float f; unsigned int i; } v; v.f = f;
  return (u16)((v.i + 0x7fffu + ((v.i >> 16) & 1u)) >> 16);  // RNE
}
// tanh-form GELU via sigmoid; |dev from erf-GELU| <= ~5e-4
__device__ __forceinline__ float gelu_f(float x) {
  float u = x * (1.5957691216057308f + 0.071354816272f * x * x);
  return x / (1.0f + __expf(-u));
}

// async global->LDS, 16B per lane. LDS dest must be wave-uniform base + lane*16.
__device__ __forceinline__ void async16(const u16* g, u16* l) {
  __builtin_amdgcn_global_load_lds(
      (const __attribute__((address_space(1))) unsigned int*)g,
      (__attribute__((address_space(3))) unsigned int*)l, 16, 0, 0);
}

// ---------------- prologue: to_nhwc(q), to_nhwc(key), border-zero x2, repack ----------
// grid: [0,8192) nhwc transposes; [8192,10256) border; [10256,11176) repack
__global__ __launch_bounds__(256) void prologue(
    const float* __restrict__ q, const float* __restrict__ key,
    const float* __restrict__ ow1, const float* __restrict__ ow2,
    const float* __restrict__ ww1, const float* __restrict__ fw1,
    const float* __restrict__ fw2,
    u16* __restrict__ qpad, u16* __restrict__ keyn, u16* __restrict__ t1pad,
    u16* __restrict__ wb) {
  __shared__ u16 l[64 * 66];
  const int id = blockIdx.x, tid = threadIdx.x;
  if (id < 8192) {
    int z = id >> 10, r = id & 1023;
    int bx = r & 3, by = r >> 2;
    const float* in; u16* out; int OW, opad;
    if (z < 4) { in = q; out = qpad; OW = WP_; opad = 1; }
    else { z -= 4; in = key; out = keyn; OW = W_; opad = 0; }
    int b = z >> 1, c0 = (z & 1) * 64;
    int h = by, w0 = bx * 64;
    for (int it = 0; it < 16; ++it) {
      int lin = it * 256 + tid;
      int c = lin >> 6, w = lin & 63;
      l[c * 66 + w] = f2bf(in[(((size_t)b * C_ + c0 + c) * H_ + h) * W_ + w0 + w]);
    }
    __syncthreads();
    int OH = (opad ? HP_ : H_);
    for (int it = 0; it < 16; ++it) {
      int lin = it * 256 + tid;
      int w = lin >> 6, c = lin & 63;
      out[(((size_t)b * OH + h + opad) * OW + (w0 + w + opad)) * C_ + c0 + c] = l[c * 66 + w];
    }
  } else if (id < 10256) {
    int j = id - 8192;
    u16* buf = (j < 1032) ? qpad : t1pad;
    int idx = ((j < 1032) ? j : j - 1032) * 256 + tid;
    int c = idx & 127;
    int t = idx >> 7;
    int pos = t % 258;
    int side = (t / 258) & 3;
    int b = t / (258 * 4);
    int h, w;
    if (side == 0) { h = 0; w = pos; }
    else if (side == 1) { h = 257; w = pos; }
    else if (side == 2) { h = pos; w = 0; }
    else { h = pos; w = 257; }
    buf[(((size_t)b * HP_ + h) * WP_ + w) * C_ + c] = 0;
  } else {
    // repack weights into wbuf (bf16):
    // W1c @0: ow1+ww1 fragment-packed [tap][cq][g 10][kb 4][lr 16][e 8] = 184320
    // W2 @184320: ow2 packed GT=1, co 8->16 zero-pad = 18432
    // fw1 @202752 row-major [co][ci] 16384 ; fw2 @219136 row-major 16384
    int idx = (id - 10256) * 256 + tid;
    float v;
    if (idx < 184320) {
      int e = idx & 7, lr = (idx >> 3) & 15, kb = (idx >> 7) & 3;
      int t = idx >> 9;
      int g = t % 10, u = t / 10;
      int cq = u & 3, tap = u >> 2;
      int ci = cq * 32 + kb * 8 + e, co = g * 16 + lr;
      v = (co < 128) ? ow1[(co * 128 + ci) * 9 + tap]
                     : ww1[((co - 128) * 128 + ci) * 9 + tap];
    } else if (idx < 202752) {
      int j = idx - 184320;
      int e = j & 7, lr = (j >> 3) & 15, kb = (j >> 7) & 3;
      int cq = (j >> 9) & 3, tap = j >> 11;
      int ci = cq * 32 + kb * 8 + e, co = lr;
      v = (co < 8) ? ow2[(co * 128 + ci) * 9 + tap] : 0.0f;
    } else if (idx < 219136) {
      v = fw1[idx - 202752];
    } else {
      v = fw2[idx - 219136];
    }
    wb[idx] = f2bf(v);
  }
}

// ---------------- combined 3x3 conv (ow1 128->128 + ww1 128->32), band-tiled ----------
// 512 threads = 8 waves; per-wave 2x5 acc tiles (40 AGPR) -> 4 waves/SIMD occupancy.
// BM=128 as 4 rows x 32 px; BN=160 (GT=10); staging 6 rows x 36 px per ci-quarter.
// XCD swizzle: id&7 owns h-bands [32*(id&7), +32).
__global__ __launch_bounds__(512, 4) void conv3_big(
    const u16* __restrict__ A, const u16* __restrict__ Wf,
    const float* __restrict__ bias1, const float* __restrict__ bias2,
    u16* __restrict__ outb, u16* __restrict__ outw) {
  constexpr int RPX = 36, ROWU = RPX * 32;          // u16 per row-plane = 1152
  __shared__ __align__(16) u16 As[6 * ROWU];        // 13,824 B
  const int tid = threadIdx.x, lane = tid & 63, wave = tid >> 6;  // 8 waves
  const int id = blockIdx.x;
  const int s = id >> 3;
  const int h0 = (((id & 7) << 3) | (s & 7)) << 2;  // 4-row band
  const int w0 = ((s >> 3) & 7) << 5;
  const int b = s >> 6;
  const int wr = wave >> 1, wc = wave & 1;          // wr: row 0..3, wc: co half
  const int wn = wc * 80;
  const int lr = lane & 15, kq = lane >> 4;
  const int gbase = wn >> 4;                        // 0 or 5

  int preA[2][3];
#pragma unroll
  for (int i = 0; i < 2; i++)
#pragma unroll
    for (int kx = 0; kx < 3; kx++) {
      int pxv = i * 16 + lr + kx;
      preA[i][kx] = (pxv * 4 + (kq ^ ((pxv >> 1) & 3))) * 8;  // u16 units
    }

  f32x4 acc[2][5];
#pragma unroll
  for (int i = 0; i < 2; i++)
#pragma unroll
    for (int j = 0; j < 5; j++) { f32x4 z = {0.f, 0.f, 0.f, 0.f}; acc[i][j] = z; }

  for (int cq = 0; cq < 4; ++cq) {
    const int ci0 = cq * 32;
    __syncthreads();
    for (int i = tid; i < 864; i += 512) {
      int ry = i / 144;
      int rem = i - ry * 144;
      int px = rem >> 2, c8 = rem & 3;
      int g = c8 ^ ((px >> 1) & 3);
      async16(A + ((size_t)(b * HP_ + h0 + ry) * WP_ + (w0 + px)) * 128 + ci0 + g * 8,
              As + i * 8);
    }
    __syncthreads();
#pragma unroll
    for (int tap = 0; tap < 9; ++tap) {
      const int ky = tap / 3, kx = tap % 3;
      bf16x8 bfr[5], af[2];
#pragma unroll
      for (int j = 0; j < 5; ++j)
        bfr[j] = *(const bf16x8*)&Wf[(size_t)((((tap * 4 + cq) * 10 + gbase + j) * 4 + kq) * 16 + lr) * 8];
#pragma unroll
      for (int i = 0; i < 2; ++i)
        af[i] = *(const bf16x8*)&As[(wr + ky) * ROWU + preA[i][kx]];
#pragma unroll
      for (int i = 0; i < 2; i++)
#pragma unroll
        for (int j = 0; j < 5; j++)
          acc[i][j] = __builtin_amdgcn_mfma_f32_16x16x32_bf16(af[i], bfr[j], acc[i][j], 0, 0, 0);
    }
  }

  const int h = h0 + wr;
#pragma unroll
  for (int i = 0; i < 2; i++) {
#pragma unroll
    for (int j = 0; j < 5; j++) {
      const int co = wn + j * 16 + lr;
#pragma unroll
      for (int r = 0; r < 4; r++) {
        const int w = w0 + i * 16 + kq * 4 + r;
        float v = acc[i][j][r];
        if (co < 128) {
          v = gelu_f(v + bias1[co]);
          outb[(((size_t)b * HP_ + h + 1) * WP_ + (w + 1)) * 128 + co] = f2bf(v);
        } else {
          v = gelu_f(v + bias2[co - 128]);
          outw[((size_t)b * P_ + (size_t)h * W_ + w) * 32 + (co - 128)] = f2bf(v);
        }
      }
    }
  }
}

// ---------------- offsets conv (3x3 128->8) + fused prep epilogue ---------------------
// BM=256 as 4 rows x 64 px; BN=16; wave = one row. Epilogue: offs->LDS regroup,
// then per-thread pixel: logits(32->4), softmax, grid math -> desc.
__global__ __launch_bounds__(256) void conv_off(
    const u16* __restrict__ A, const u16* __restrict__ Wf,
    const float* __restrict__ bias,
    const u16* __restrict__ w1b, const float* __restrict__ ww2,
    const float* __restrict__ wb2, uint4* __restrict__ desc) {
  constexpr int RPX = 66, ROWU = RPX * 32;          // 2112 u16 per row-plane
  __shared__ __align__(16) u16 As[6 * ROWU];        // 25,344 B
  float* off_lds = (float*)As;                      // reused after K-loop (256*9*4 B)
  const int tid = threadIdx.x, lane = tid & 63, wave = tid >> 6;
  const int id = blockIdx.x;
  const int s = id >> 3;
  const int h0 = (((id & 7) << 3) | (s & 7)) << 2;
  const int w0 = ((s >> 3) & 3) << 6;
  const int b = s >> 5;
  const int lr = lane & 15, kq = lane >> 4;

  int preA[4][3];
#pragma unroll
  for (int i = 0; i < 4; i++)
#pragma unroll
    for (int kx = 0; kx < 3; kx++) {
      int pxv = i * 16 + lr + kx;
      preA[i][kx] = (pxv * 4 + (kq ^ ((pxv >> 1) & 3))) * 8;
    }

  f32x4 acc[4];
#pragma unroll
  for (int i = 0; i < 4; i++) { f32x4 z = {0.f, 0.f, 0.f, 0.f}; acc[i] = z; }

  for (int cq = 0; cq < 4; ++cq) {
    const int ci0 = cq * 32;
    __syncthreads();
    for (int i = tid; i < 1584; i += 256) {
      int ry = i / 264;
      int rem = i - ry * 264;
      int px = rem >> 2, c8 = rem & 3;
      int g = c8 ^ ((px >> 1) & 3);
      async16(A + ((size_t)(b * HP_ + h0 + ry) * WP_ + (w0 + px)) * 128 + ci0 + g * 8,
              As + i * 8);
    }
    __syncthreads();
#pragma unroll
    for (int tap = 0; tap < 9; ++tap) {
      const int ky = tap / 3, kx = tap % 3;
      bf16x8 bw = *(const bf16x8*)&Wf[(size_t)(((tap * 4 + cq) * 4 + kq) * 16 + lr) * 8];
      bf16x8 af[4];
#pragma unroll
      for (int i = 0; i < 4; ++i)
        af[i] = *(const bf16x8*)&As[(wave + ky) * ROWU + preA[i][kx]];
#pragma unroll
      for (int i = 0; i < 4; i++)
        acc[i] = __builtin_amdgcn_mfma_f32_16x16x32_bf16(af[i], bw, acc[i], 0, 0, 0);
    }
  }

  __syncthreads();  // staging region dead; reuse as off_lds
#pragma unroll
  for (int i = 0; i < 4; i++) {
#pragma unroll
    for (int r = 0; r < 4; r++) {
      if (lr < 8) {
        int px = i * 16 + (lane >> 4) * 4 + r;
        off_lds[(wave * 64 + px) * 9 + lr] = acc[i][r] + bias[lr];
      }
    }
  }
  __syncthreads();

  // one pixel per thread
  const int pp = tid;
  const int h = h0 + (pp >> 6), w = w0 + (pp & 63);
  const int pix = b * P_ + h * W_ + w;
  const u16* wp = w1b + (size_t)pix * 32;
  float f[32];
#pragma unroll
  for (int i = 0; i < 32; i += 2) {
    unsigned u = *(const unsigned*)&wp[i];
    f[i] = bf2f((u16)u); f[i + 1] = bf2f((u16)(u >> 16));
  }
  float lg[4];
#pragma unroll
  for (int k = 0; k < 4; k++) {
    float sacc = wb2[k];
#pragma unroll
    for (int i = 0; i < 32; i++) sacc = fmaf(ww2[k * 32 + i], f[i], sacc);
    lg[k] = sacc;
  }
  float mx = fmaxf(fmaxf(lg[0], lg[1]), fmaxf(lg[2], lg[3]));
  float e[4], sum = 0.f;
#pragma unroll
  for (int k = 0; k < 4; k++) { e[k] = __expf(lg[k] - mx); sum += e[k]; }
  const float inv = 1.0f / sum;
#pragma unroll
  for (int k = 0; k < 4; k++) {
    float ox = off_lds[pp * 9 + 2 * k], oy = off_lds[pp * 9 + 2 * k + 1];
    float gx = (2.0f * w / 255.0f - 1.0f) + ox * (1.0f / 128.0f);
    float gy = (2.0f * h / 255.0f - 1.0f) + oy * (1.0f / 128.0f);
    gx = fminf(fmaxf(gx, -1.f), 1.f);
    gy = fminf(fmaxf(gy, -1.f), 1.f);
    float px = fminf(fmaxf((gx + 1.f) * 127.5f, 0.f), 255.f);
    float py = fminf(fmaxf((gy + 1.f) * 127.5f, 0.f), 255.f);
    int x0 = (int)px, y0 = (int)py;
    int x1 = min(x0 + 1, 255), y1 = min(y0 + 1, 255);
    float wx = px - x0, wy = py - y0;
    float wk = e[k] * inv;
    float w00 = (1.f - wx) * (1.f - wy) * wk, w01 = wx * (1.f - wy) * wk;
    float w10 = (1.f - wx) * wy * wk,         w11 = wx * wy * wk;
    HU t01, t23;
    t01.h = __floats2half2_rn(w00, w01);
    t23.h = __floats2half2_rn(w10, w11);
    uint4 d;
    d.x = (unsigned)(y0 * 256 + x0) | ((unsigned)(x1 - x0) << 16) | ((unsigned)(y1 - y0) << 17);
    d.y = t01.u; d.z = t23.u; d.w = 0;
    desc[(size_t)pix * 4 + k] = d;
  }
}

// ---------------- sampler: wave per pixel, lane = channel pair ------------------------
__global__ __launch_bounds__(256) void sampler(
    const uint4* __restrict__ desc, const u16* __restrict__ keyn, u16* __restrict__ agg) {
  const int tid = threadIdx.x, lane = tid & 63, wv = tid >> 6;
  const int pix = blockIdx.x * 4 + wv;
  const int b = pix >> 16;
  const u16* kb = keyn + (size_t)b * (P_ * C_) + 2 * lane;
  float a0 = 0.f, a1 = 0.f;
#pragma unroll
  for (int k = 0; k < 4; ++k) {
    uint4 d = desc[(size_t)pix * 4 + k];
    const int boff = (int)(d.x & 0xFFFFu) << 7;
    const int o01 = (int)((d.x >> 16) & 1u) << 7;
    const int o10 = (int)((d.x >> 17) & 1u) << 15;
    const u16* c0 = kb + boff;
    unsigned u00 = *(const unsigned*)(c0);
    unsigned u01 = *(const unsigned*)(c0 + o01);
    unsigned u10 = *(const unsigned*)(c0 + o10);
    unsigned u11 = *(const unsigned*)(c0 + o10 + o01);
    HU t01, t23; t01.u = d.y; t23.u = d.z;
    float2 wA = __half22float2(t01.h);
    float2 wB = __half22float2(t23.h);
    a0 = fmaf(wA.x, bf2f((u16)u00), a0);
    a0 = fmaf(wA.y, bf2f((u16)u01), a0);
    a0 = fmaf(wB.x, bf2f((u16)u10), a0);
    a0 = fmaf(wB.y, bf2f((u16)u11), a0);
    a1 = fmaf(wA.x, bf2f((u16)(u00 >> 16)), a1);
    a1 = fmaf(wA.y, bf2f((u16)(u01 >> 16)), a1);
    a1 = fmaf(wB.x, bf2f((u16)(u10 >> 16)), a1);
    a1 = fmaf(wB.y, bf2f((u16)(u11 >> 16)), a1);
  }
  unsigned outu = ((unsigned)f2bf(a1) << 16) | (unsigned)f2bf(a0);
  *(unsigned*)&agg[(size_t)pix * C_ + 2 * lane] = outu;
}

// ---------------- fused fusion: 1x1 conv + GELU -> LDS -> 1x1 conv + residual ---------
// 512 threads = 8 waves; per-wave 2x4 acc tiles (32 AGPR) -> 4 waves/SIMD occupancy.
// block = 128 px x 128 co (all of K for GEMM2 is produced in-block).
__global__ __launch_bounds__(512, 4) void conv_fuse(
    const u16* __restrict__ Aagg, const u16* __restrict__ W1, const u16* __restrict__ W2,
    const float* __restrict__ b1, const float* __restrict__ b2,
    const float* __restrict__ resid, float* __restrict__ out) {
  __shared__ __align__(16) u16 SM[16384];   // phase1: As[0:8192) Bs[8192:16384); phase2: Bs2
  __shared__ __align__(16) u16 T2[128 * 136];  // GELU tile, px pitch 136 u16 (272B)
  u16* As = SM;
  u16* Bs = SM + 8192;
  const int tid = threadIdx.x, lane = tid & 63, wave = tid >> 6;  // 8 waves
  const int h = blockIdx.y, w0 = blockIdx.x * 128;
  const int b = blockIdx.z;
  const int wr = wave >> 1, wc = wave & 1;
  const int wm = wr * 32, wn = wc * 64;
  const int lr = lane & 15, kq = lane >> 4;
  const int sw = lr & 7;

  f32x4 acc[2][4];
#pragma unroll
  for (int i = 0; i < 2; i++)
#pragma unroll
    for (int j = 0; j < 4; j++) { f32x4 z = {0.f, 0.f, 0.f, 0.f}; acc[i][j] = z; }

  // ---- GEMM1: agg(128px x 128ci) @ fw1 -> acc
  for (int c = 0; c < 2; ++c) {
    const int ci0 = c << 6;
    const u16* Ab = Aagg + (((size_t)b * H_ + h) * W_ + w0) * 128 + ci0;
    const u16* Wb = W1 + ci0;
    __syncthreads();
    for (int i = tid; i < 128 * 8; i += 512) {
      int r = i >> 3, cb = i & 7;
      async16(Ab + r * 128 + ((cb ^ (r & 7)) << 3), As + i * 8);
    }
    for (int i = tid; i < 128 * 8; i += 512) {
      int r = i >> 3, cb = i & 7;
      async16(Wb + r * 128 + ((cb ^ (r & 7)) << 3), Bs + i * 8);
    }
    __syncthreads();
#pragma unroll
    for (int ks = 0; ks < 2; ++ks) {
      const int kb = ks * 4 + kq;
      bf16x8 af[2], bfr[4];
#pragma unroll
      for (int i = 0; i < 2; i++)
        af[i] = *(const bf16x8*)&As[(wm + i * 16 + lr) * 64 + ((kb ^ sw) << 3)];
#pragma unroll
      for (int j = 0; j < 4; j++)
        bfr[j] = *(const bf16x8*)&Bs[(wn + j * 16 + lr) * 64 + ((kb ^ sw) << 3)];
#pragma unroll
      for (int i = 0; i < 2; i++)
#pragma unroll
        for (int j = 0; j < 4; j++)
          acc[i][j] = __builtin_amdgcn_mfma_f32_16x16x32_bf16(af[i], bfr[j], acc[i][j], 0, 0, 0);
    }
  }

  // ---- GELU -> T2 (bf16), then stage fw2 into SM
#pragma unroll
  for (int i = 0; i < 2; i++)
#pragma unroll
    for (int j = 0; j < 4; j++) {
      const int co = wn + j * 16 + lr;
#pragma unroll
      for (int r = 0; r < 4; r++) {
        const int px = wm + i * 16 + kq * 4 + r;
        T2[px * 136 + co] = f2bf(gelu_f(acc[i][j][r] + b1[co]));
      }
    }
  __syncthreads();
  for (int i = tid; i < 2048; i += 512) {   // 128co x 16 chunks
    int r = i >> 4, sl = i & 15;
    int g = sl ^ (r & 7);
    async16(W2 + r * 128 + g * 8, SM + i * 8);
  }
  __syncthreads();

  // ---- GEMM2: T2(128px x 128k) @ fw2 -> acc
#pragma unroll
  for (int i = 0; i < 2; i++)
#pragma unroll
    for (int j = 0; j < 4; j++) { f32x4 z = {0.f, 0.f, 0.f, 0.f}; acc[i][j] = z; }
#pragma unroll
  for (int ks = 0; ks < 4; ++ks) {
    const int kc = ks * 4 + kq;
    bf16x8 af[2], bfr[4];
#pragma unroll
    for (int i = 0; i < 2; i++)
      af[i] = *(const bf16x8*)&T2[(wm + i * 16 + lr) * 136 + kc * 8];
#pragma unroll
    for (int j = 0; j < 4; j++) {
      int rr = wn + j * 16 + lr;
      bfr[j] = *(const bf16x8*)&SM[rr * 128 + (kc ^ (rr & 7)) * 8];
    }
#pragma unroll
    for (int i = 0; i < 2; i++)
#pragma unroll
      for (int j = 0; j < 4; j++)
        acc[i][j] = __builtin_amdgcn_mfma_f32_16x16x32_bf16(af[i], bfr[j], acc[i][j], 0, 0, 0);
  }

  // ---- residual epilogue (fp32 NCHW)
#pragma unroll
  for (int i = 0; i < 2; i++) {
#pragma unroll
    for (int j = 0; j < 4; j++) {
      const int co = wn + j * 16 + lr;
      const int w = w0 + wm + i * 16 + kq * 4;
      size_t idx = ((size_t)b * 128 + co) * (size_t)P_ + (size_t)h * W_ + w;
      float4 rv = *(const float4*)&resid[idx];
      float bi = b2[co];
      float4 ov;
      ov.x = rv.x + 0.3f * (acc[i][j][0] + bi);
      ov.y = rv.y + 0.3f * (acc[i][j][1] + bi);
      ov.z = rv.z + 0.3f * (acc[i][j][2] + bi);
      ov.w = rv.w + 0.3f * (acc[i][j][3] + bi);
      *(float4*)&out[idx] = ov;
    }
  }
}

extern "C" void kernel_launch(void* const* d_in, const int* in_sizes, int n_in,
                              void* d_out, int out_size, void* d_ws, size_t ws_size,
                              hipStream_t stream) {
  (void)in_sizes; (void)n_in; (void)out_size; (void)ws_size;
  const float* q   = (const float*)d_in[0];
  const float* key = (const float*)d_in[1];
  const float* ow1 = (const float*)d_in[2];
  const float* ob1 = (const float*)d_in[3];
  const float* ow2 = (const float*)d_in[4];
  const float* ob2 = (const float*)d_in[5];
  const float* ww1 = (const float*)d_in[6];
  const float* wb1 = (const float*)d_in[7];
  const float* ww2 = (const float*)d_in[8];
  const float* wb2 = (const float*)d_in[9];
  const float* fw1 = (const float*)d_in[10];
  const float* fb1 = (const float*)d_in[11];
  const float* fw2 = (const float*)d_in[12];
  const float* fb2 = (const float*)d_in[13];
  float* out = (float*)d_out;
  char* ws = (char*)d_ws;

  // workspace: qpad @0 (34.08MB, reused as desc after conv3_big); t1pad @34080768
  // (34.08MB, reused as agg); keyn @68161536 (33.55MB); w1b @101715968 (8.39MB);
  // wbuf @110104576 (471KB). peak 110.6MB.
  u16* qpad  = (u16*)(ws);
  u16* t1pad = (u16*)(ws + 34080768);
  u16* keyn  = (u16*)(ws + 68161536);
  u16* w1b   = (u16*)(ws + 101715968);
  u16* wbuf  = (u16*)(ws + 110104576);
  uint4* desc = (uint4*)ws;        // qpad dead after conv3_big
  u16* agg = t1pad;                // t1pad dead after conv_off

  prologue<<<11176, 256, 0, stream>>>(q, key, ow1, ow2, ww1, fw1, fw2,
                                      qpad, keyn, t1pad, wbuf);
  conv3_big<<<1024, 512, 0, stream>>>(qpad, wbuf, ob1, wb1, t1pad, w1b);
  conv_off<<<512, 256, 0, stream>>>(t1pad, wbuf + 184320, ob2, w1b, ww2, wb2, desc);
  sampler<<<32768, 256, 0, stream>>>(desc, keyn, agg);
  conv_fuse<<<dim3(2, 256, 2), 512, 0, stream>>>(agg, wbuf + 202752, wbuf + 219136,
                                                 fb1, fb2, q, out);
}